// Round 14
// baseline (638.863 us; speedup 1.0000x reference)
//
#include <hip/hip_runtime.h>
#include <stdint.h>

// ---------------------------------------------------------------------------
// EnhancedSNNCifar: T=8 SNN forward.
// R14: occupancy retune of big-tile convs (R13's conv2 was write-drain-bound
//      at 2-3 blocks/CU, LDS 49.7KB). conv2 ROWS 16->8 (27.5KB, 5/CU, 4096
//      blocks), conv3 IMPB 2->1 (25.9KB, 6/CU), conv4 ROWS 16->8 w/ KSPLIT=2
//      (25.9KB, 6/CU). Math identical -> absmax 0.0. conv5/6/fc unchanged.
// ---------------------------------------------------------------------------

#define T_STEPS 8
#define NBATCH 128

typedef __attribute__((ext_vector_type(8))) short short8;
typedef __attribute__((ext_vector_type(4))) float f32x4;

__device__ __forceinline__ uint16_t f2bf(float f) {
    uint32_t x = __float_as_uint(f);
    uint32_t r = x + 0x7FFFu + ((x >> 16) & 1u);
    return (uint16_t)(r >> 16);
}
__device__ __forceinline__ float bf2f(uint16_t h) {
    return __uint_as_float(((uint32_t)h) << 16);
}

// ---------------------------------------------------------------------------
// Merged weight prep (5 convs + fc1) + stats zeroing, triple-bf16-split.
// ---------------------------------------------------------------------------
__device__ __forceinline__ void tsplit(float v, uint16_t& h1, uint16_t& h2, uint16_t& h3) {
    h1 = f2bf(v);
    const float r1 = v - bf2f(h1);
    h2 = f2bf(r1);
    const float r2 = r1 - bf2f(h2);
    h3 = f2bf(r2);
}

__device__ __forceinline__ void prep_conv_one(const float* __restrict__ w,
                                              uint16_t* __restrict__ wp, int i, int CIN) {
    const int KC = CIN >> 5;
    const int sh = i % 9;
    const int ci = (i / 9) % CIN;
    const int co = i / (9 * CIN);
    uint16_t h1, h2, h3;
    tsplit(w[i], h1, h2, h3);
    uint16_t* base = wp + (size_t)((co >> 4) * KC + (ci >> 5)) * 14976
                        + sh * 1664 + (co & 15) * 104 + (ci & 31);
    base[0] = h1;
    base[32] = h2;
    base[64] = h3;
}

__device__ __forceinline__ void prep_fc1_one(const float* __restrict__ w,
                                             uint16_t* __restrict__ wp, int i) {
    const int kp = i & 2047;
    const int o = i >> 11;
    const int px = kp >> 7, c = kp & 127;
    uint16_t h1, h2, h3;
    tsplit(w[o * 2048 + c * 16 + px], h1, h2, h3);
    uint16_t* base = wp + (size_t)((o >> 4) * 64 + (kp >> 5)) * 1664
                        + (o & 15) * 104 + (kp & 31);
    base[0] = h1;
    base[32] = h2;
    base[64] = h3;
}

__global__ void prep_all_kernel(const float* __restrict__ W2, const float* __restrict__ W3,
                                const float* __restrict__ W4, const float* __restrict__ W5,
                                const float* __restrict__ W6, const float* __restrict__ F1,
                                uint16_t* __restrict__ P2, uint16_t* __restrict__ P3,
                                uint16_t* __restrict__ P4, uint16_t* __restrict__ P5,
                                uint16_t* __restrict__ P6, uint16_t* __restrict__ PF,
                                float* __restrict__ stats) {
    int i = blockIdx.x * blockDim.x + threadIdx.x;
    if (i < 1536) { stats[i] = 0.0f; return; }
    i -= 1536;
    if (i < 9216) { prep_conv_one(W2, P2, i, 32); return; }
    i -= 9216;
    if (i < 18432) { prep_conv_one(W3, P3, i, 32); return; }
    i -= 18432;
    if (i < 36864) { prep_conv_one(W4, P4, i, 64); return; }
    i -= 36864;
    if (i < 73728) { prep_conv_one(W5, P5, i, 64); return; }
    i -= 73728;
    if (i < 147456) { prep_conv_one(W6, P6, i, 128); return; }
    i -= 147456;
    if (i < 262144) prep_fc1_one(F1, PF, i);
}

// Merged halo-border zeroing for all 6 u8 spike arrays (4 ch per thread).
__global__ void border_all_kernel(uint8_t* S1, uint8_t* S2, uint8_t* S3,
                                  uint8_t* S4, uint8_t* S5, uint8_t* S6) {
    int i = blockIdx.x * blockDim.x + threadIdx.x;
    uint8_t* s;
    int C, HP, WPP;
    if (i < 1081344) { s = S1; C = 32; HP = 34; WPP = 34; }
    else if ((i -= 1081344) < 557056) { s = S2; C = 32; HP = 18; WPP = 18; }
    else if ((i -= 557056) < 1114112) { s = S3; C = 64; HP = 18; WPP = 18; }
    else if ((i -= 1114112) < 589824) { s = S4; C = 64; HP = 10; WPP = 10; }
    else if ((i -= 589824) < 1179648) { s = S5; C = 128; HP = 10; WPP = 10; }
    else if ((i -= 1179648) < 655360) { s = S6; C = 128; HP = 6; WPP = 6; }
    else return;
    const int C4 = C >> 2;
    const int NB = 2 * WPP + 2 * (HP - 2);
    const int c4 = i % C4;
    const int b = (i / C4) % NB;
    const int img = i / (C4 * NB);
    int py, px;
    if (b < WPP) { py = 0; px = b; }
    else if (b < 2 * WPP) { py = HP - 1; px = b - WPP; }
    else { const int r = b - 2 * WPP; py = 1 + (r >> 1); px = (r & 1) ? (WPP - 1) : 0; }
    *(uint32_t*)&s[(size_t)img * (HP * WPP * C) + (py * WPP + px) * C + 4 * c4] = 0u;
}

// ---------------------------------------------------------------------------
// conv1 (3->32, 32x32, fp32 NCHW input): block 256 = 8 strips x 32 co.
// ---------------------------------------------------------------------------
__global__ __launch_bounds__(256) void conv1_kernel(
    const float* __restrict__ x, const float* __restrict__ w,
    const float* __restrict__ bias, float* __restrict__ y,
    float* __restrict__ ssum, float* __restrict__ ssq)
{
    __shared__ float tile[3][10][34];
    __shared__ float bnl[64];
    const int tid = threadIdx.x;
    const int m = blockIdx.x;
    const int y0 = blockIdx.y * 8;
    const int co = tid & 31;
    const int strip = tid >> 5;

    if (tid < 64) bnl[tid] = 0.0f;
    for (int i = tid; i < 3 * 10 * 34; i += 256) ((float*)tile)[i] = 0.0f;
    __syncthreads();

    {
        const int gy0 = (y0 == 0) ? 0 : y0 - 1;
        const int gy1 = (y0 + 8 > 31) ? 31 : y0 + 8;
        const int nrows = gy1 - gy0 + 1;
        for (int i = tid; i < 3 * nrows * 32; i += 256) {
            const int gx = i & 31;
            const int r = (i >> 5) % nrows;
            const int ci = i / (32 * nrows);
            const int gy = gy0 + r;
            tile[ci][gy - y0 + 1][gx + 1] =
                x[((size_t)m * 3 + ci) * 1024 + gy * 32 + gx];
        }
    }
    __syncthreads();

    float wr[27];
#pragma unroll
    for (int j = 0; j < 27; ++j) wr[j] = w[co * 27 + j];
    const float bv = bias[co];

    float lsum = 0.0f, lsq = 0.0f;
#pragma unroll
    for (int g = 0; g < 8; ++g) {
        float s[3][3][6];
#pragma unroll
        for (int ci = 0; ci < 3; ++ci)
#pragma unroll
            for (int ky = 0; ky < 3; ++ky)
#pragma unroll
                for (int c = 0; c < 6; ++c)
                    s[ci][ky][c] = tile[ci][g + ky][strip * 4 + c];
#pragma unroll
        for (int r = 0; r < 4; ++r) {
            float acc = bv;
#pragma unroll
            for (int ci = 0; ci < 3; ++ci)
#pragma unroll
                for (int ky = 0; ky < 3; ++ky)
#pragma unroll
                    for (int kx = 0; kx < 3; ++kx)
                        acc += s[ci][ky][r + kx] * wr[ci * 9 + ky * 3 + kx];
            const int lx = strip * 4 + r;
            y[(((size_t)m * 1024) + (y0 + g) * 32 + lx) * 32 + co] = acc;
            lsum += acc;
            lsq += acc * acc;
        }
    }
    atomicAdd(&bnl[co], lsum);
    atomicAdd(&bnl[32 + co], lsq);
    __syncthreads();
    if (tid < 32) atomicAdd(&ssum[tid], bnl[tid]);
    else if (tid < 64) atomicAdd(&ssq[tid - 32], bnl[tid]);
}

// ---------------------------------------------------------------------------
// MFMA spike conv. in: padded u8 spikes [m][(H+2)(W+2)][CIN] (halo zero).
// grid = ((M/IMPB)*(H/ROWS), COUT/(16*NCO)), block 256 (4 waves).
// ---------------------------------------------------------------------------
template <int CIN, int COUT, int H, int W, int ROWS, int IMPB, int NCO, int KSPLIT>
__global__ __launch_bounds__(256) void conv_mfma_kernel(
    const uint8_t* __restrict__ in, const uint16_t* __restrict__ wp,
    const float* __restrict__ bias, float* __restrict__ y,
    float* __restrict__ ssum, float* __restrict__ ssq)
{
    constexpr int KC = CIN / 32;
    constexpr int WPP = W + 2;
    constexpr int HW = H * W;
    constexpr int PXU16 = CIN + 8;
    constexpr int ISTR_B = (H + 2) * WPP * CIN;
    constexpr int RB = H / ROWS;
    constexpr int NSTRIP = IMPB * ROWS * W / 16;
    constexpr int MSPLIT = 4 / KSPLIT;
    constexpr int SPW = NSTRIP / MSPLIT;
    constexpr int TILE_U16 = IMPB * (ROWS + 2) * WPP * PXU16;
    constexpr int TILE_B = IMPB * (ROWS + 2) * WPP * CIN;
    constexpr int NIT = KC * 9;
    constexpr int ITW = NIT / KSPLIT;
    constexpr int CS = NCO * 16 + 1;
    static_assert(IMPB == 1 || ROWS == H, "impb needs full-image tiles");
    static_assert(NSTRIP % MSPLIT == 0 && NSTRIP % 4 == 0, "strips");
    static_assert(NIT % KSPLIT == 0, "ksplit");
    static_assert(TILE_B % 16 == 0, "tile u8 16B");
    static_assert(KSPLIT == 1 || TILE_U16 * 2 >= NSTRIP * 16 * CS * 4, "C fits");

    __shared__ __align__(16) uint16_t sp[TILE_U16];
    __shared__ float bn[NCO * 32];

    const int tid = threadIdx.x;
    const int lane = tid & 63;
    const int wav = tid >> 6;
    const int kg = wav / MSPLIT;
    const int mg = wav - kg * MSPLIT;
    const int col = lane & 15;
    const int quad = lane >> 4;

    const int m0 = (blockIdx.x / RB) * IMPB;
    const int ybase = (blockIdx.x % RB) * ROWS;

    if (tid < NCO * 32) bn[tid] = 0.0f;

    // ---- stage spike tile: u8 -> bf16 expand ----
    {
        const uint8_t* src = in + (size_t)m0 * ISTR_B + (size_t)ybase * WPP * CIN;
        for (int i = tid; i < TILE_B / 16; i += 256) {
            const uint4 v = ((const uint4*)src)[i];
            const int b = i * 16;
            const int px = b / CIN;
            const int ci = b - px * CIN;
            uint32_t* d = (uint32_t*)&sp[px * PXU16 + ci];
            d[0] = ((v.x & 1u) | (((v.x >> 8) & 1u) << 16)) * 0x3F80u;
            d[1] = (((v.x >> 16) & 1u) | (((v.x >> 24) & 1u) << 16)) * 0x3F80u;
            d[2] = ((v.y & 1u) | (((v.y >> 8) & 1u) << 16)) * 0x3F80u;
            d[3] = (((v.y >> 16) & 1u) | (((v.y >> 24) & 1u) << 16)) * 0x3F80u;
            d[4] = ((v.z & 1u) | (((v.z >> 8) & 1u) << 16)) * 0x3F80u;
            d[5] = (((v.z >> 16) & 1u) | (((v.z >> 24) & 1u) << 16)) * 0x3F80u;
            d[6] = ((v.w & 1u) | (((v.w >> 8) & 1u) << 16)) * 0x3F80u;
            d[7] = (((v.w >> 16) & 1u) | (((v.w >> 24) & 1u) << 16)) * 0x3F80u;
        }
    }
    __syncthreads();

    int abase[SPW];
#pragma unroll
    for (int s = 0; s < SPW; ++s) {
        const int p = (mg * SPW + s) * 16 + col;
        const int img = p / (ROWS * W);
        const int rem = p % (ROWS * W);
        abase[s] = ((img * (ROWS + 2) + rem / W) * WPP + rem % W) * PXU16 + quad * 8;
    }

    f32x4 acc[SPW][NCO];
#pragma unroll
    for (int s = 0; s < SPW; ++s)
#pragma unroll
        for (int j = 0; j < NCO; ++j) acc[s][j] = (f32x4)0.0f;

    const uint16_t* wbase = wp + ((size_t)blockIdx.y * NCO * KC) * 14976
                               + col * 104 + quad * 8;

    auto loadB = [&](short8 (&buf)[NCO][3], int it) {
        const int kc = it / 9, sh = it - kc * 9;
#pragma unroll
        for (int j = 0; j < NCO; ++j) {
            const uint16_t* p = wbase + (size_t)(j * KC + kc) * 14976 + sh * 1664;
            buf[j][0] = *(const short8*)p;
            buf[j][1] = *(const short8*)(p + 32);
            buf[j][2] = *(const short8*)(p + 64);
        }
    };
    auto mfmaStep = [&](short8 (&buf)[NCO][3], int it) {
        const int kc = it / 9, sh = it - kc * 9;
        const int dy = sh / 3, dx = sh - dy * 3;
        const int shoff = (dy * WPP + dx) * PXU16 + kc * 32;
#pragma unroll
        for (int s = 0; s < SPW; ++s) {
            const short8 a = *(const short8*)&sp[abase[s] + shoff];
#pragma unroll
            for (int j = 0; j < NCO; ++j) {
                f32x4 t = acc[s][j];
                t = __builtin_amdgcn_mfma_f32_16x16x32_bf16(a, buf[j][0], t, 0, 0, 0);
                t = __builtin_amdgcn_mfma_f32_16x16x32_bf16(a, buf[j][1], t, 0, 0, 0);
                t = __builtin_amdgcn_mfma_f32_16x16x32_bf16(a, buf[j][2], t, 0, 0, 0);
                acc[s][j] = t;
            }
        }
    };

    short8 bufA[NCO][3], bufB[NCO][3];
    const int it0 = kg * ITW, it1 = it0 + ITW;
    loadB(bufA, it0);
    int it = it0;
#pragma unroll 1
    for (; it + 2 <= it1; it += 2) {
        loadB(bufB, it + 1);
        mfmaStep(bufA, it);
        if (it + 2 < it1) loadB(bufA, it + 2);
        mfmaStep(bufB, it + 1);
    }
    if (it < it1) mfmaStep(bufA, it);

    float bv[NCO];
#pragma unroll
    for (int j = 0; j < NCO; ++j) bv[j] = bias[(blockIdx.y * NCO + j) * 16 + col];

    if constexpr (KSPLIT == 1) {
#pragma unroll
        for (int s = 0; s < SPW; ++s) {
            const int pb_ = (mg * SPW + s) * 16 + quad * 4;
            float sum[NCO], sq[NCO];
#pragma unroll
            for (int j = 0; j < NCO; ++j) { sum[j] = 0.0f; sq[j] = 0.0f; }
#pragma unroll
            for (int r = 0; r < 4; ++r) {
                const int p = pb_ + r;
                const int img = p / (ROWS * W);
                const int pxim = p % (ROWS * W) + ybase * W;
                float* yp = &y[((size_t)(m0 + img) * HW + pxim) * COUT
                               + blockIdx.y * NCO * 16 + col];
#pragma unroll
                for (int j = 0; j < NCO; ++j) {   // j innermost: 128B line merge
                    const float v = acc[s][j][r] + bv[j];
                    yp[j * 16] = v;
                    sum[j] += v;
                    sq[j] += v * v;
                }
            }
#pragma unroll
            for (int j = 0; j < NCO; ++j) {
                float su = sum[j], s2 = sq[j];
                su += __shfl_xor(su, 16, 64);
                su += __shfl_xor(su, 32, 64);
                s2 += __shfl_xor(s2, 16, 64);
                s2 += __shfl_xor(s2, 32, 64);
                if (quad == 0) {
                    atomicAdd(&bn[j * 32 + col], su);
                    atomicAdd(&bn[j * 32 + 16 + col], s2);
                }
            }
        }
    } else {
        float* Csh = (float*)sp;
        __syncthreads();
        if (kg == 0) {
#pragma unroll
            for (int s = 0; s < SPW; ++s)
#pragma unroll
                for (int j = 0; j < NCO; ++j)
#pragma unroll
                    for (int r = 0; r < 4; ++r)
                        Csh[((mg * SPW + s) * 16 + quad * 4 + r) * CS + j * 16 + col]
                            = acc[s][j][r];
        }
        __syncthreads();
#pragma unroll
        for (int k = 1; k < KSPLIT; ++k) {
            if (kg == k) {
#pragma unroll
                for (int s = 0; s < SPW; ++s)
#pragma unroll
                    for (int j = 0; j < NCO; ++j)
#pragma unroll
                        for (int r = 0; r < 4; ++r)
                            Csh[((mg * SPW + s) * 16 + quad * 4 + r) * CS + j * 16 + col]
                                += acc[s][j][r];
            }
            __syncthreads();
        }
        constexpr int ES = NSTRIP / 4;
#pragma unroll
        for (int s2i = 0; s2i < ES; ++s2i) {
            const int gs = wav * ES + s2i;
            float sum[NCO], sq[NCO];
#pragma unroll
            for (int j = 0; j < NCO; ++j) { sum[j] = 0.0f; sq[j] = 0.0f; }
#pragma unroll
            for (int r = 0; r < 4; ++r) {
                const int p = gs * 16 + quad * 4 + r;
                const int img = p / (ROWS * W);
                const int pxim = p % (ROWS * W) + ybase * W;
                float* yp = &y[((size_t)(m0 + img) * HW + pxim) * COUT
                               + blockIdx.y * NCO * 16 + col];
#pragma unroll
                for (int j = 0; j < NCO; ++j) {
                    const float v = Csh[p * CS + j * 16 + col] + bv[j];
                    yp[j * 16] = v;
                    sum[j] += v;
                    sq[j] += v * v;
                }
            }
#pragma unroll
            for (int j = 0; j < NCO; ++j) {
                float su = sum[j], s2 = sq[j];
                su += __shfl_xor(su, 16, 64);
                su += __shfl_xor(su, 32, 64);
                s2 += __shfl_xor(s2, 16, 64);
                s2 += __shfl_xor(s2, 32, 64);
                if (quad == 0) {
                    atomicAdd(&bn[j * 32 + col], su);
                    atomicAdd(&bn[j * 32 + 16 + col], s2);
                }
            }
        }
    }
    __syncthreads();
    if (tid < NCO * 32) {
        const int j = tid >> 5, r = tid & 31;
        const int co0 = (blockIdx.y * NCO + j) * 16;
        if (r < 16) atomicAdd(&ssum[co0 + r], bn[j * 32 + r]);
        else atomicAdd(&ssq[co0 + r - 16], bn[j * 32 + r]);
    }
}

// Layer-1 BN+LIF: y NHWC [N][1024][32] (T-invariant) -> padded u8 spikes.
__global__ void bnlif1_pad_kernel(const float* __restrict__ y,
                                  const float* __restrict__ ssum,
                                  const float* __restrict__ ssq,
                                  const float* __restrict__ g,
                                  const float* __restrict__ be,
                                  uint8_t* __restrict__ s, float invM) {
    constexpr int OSTR = 34 * 34 * 32;
    const int i = blockIdx.x * blockDim.x + threadIdx.x;
    if (i >= NBATCH * 1024 * 8) return;
    const int c4 = i & 7;
    const int px = (i >> 3) & 1023;
    const int n = i >> 13;
    const int c0 = 4 * c4;
    float z[4], v[4];
    const float4 q = *(const float4*)&y[((size_t)n * 1024 + px) * 32 + c0];
    const float* qf = (const float*)&q;
#pragma unroll
    for (int c = 0; c < 4; ++c) {
        const float m = ssum[c0 + c] * invM;
        const float inv = g[c0 + c] / sqrtf(ssq[c0 + c] * invM - m * m + 1e-5f);
        z[c] = qf[c] * inv + (be[c0 + c] - m * inv);
        v[c] = 0.0f;
    }
    const int pyy = px >> 5, pxx = px & 31;
    const size_t obase = (size_t)n * OSTR + ((pyy + 1) * 34 + pxx + 1) * 32 + c0;
    const size_t ot = (size_t)NBATCH * OSTR;
#pragma unroll
    for (int t = 0; t < T_STEPS; ++t) {
        uint32_t pk = 0;
#pragma unroll
        for (int c = 0; c < 4; ++c) {
            v[c] += (z[c] - v[c]) * 0.5f;
            if (v[c] >= 1.0f) { v[c] = 0.0f; pk |= 1u << (8 * c); }
        }
        *(uint32_t*)&s[t * ot + obase] = pk;
    }
}

// BN+LIF (no pool): y NHWC [T*N][HW][C] -> padded u8 spikes (4 ch/thread).
template <int C, int H, int W>
__global__ void bnlif_pad_kernel(const float* __restrict__ y,
                                 const float* __restrict__ ssum,
                                 const float* __restrict__ ssq,
                                 const float* __restrict__ g,
                                 const float* __restrict__ be,
                                 uint8_t* __restrict__ s, float invM) {
    constexpr int C4 = C / 4;
    constexpr int HW = H * W;
    constexpr int OSTR = (H + 2) * (W + 2) * C;
    const int i = blockIdx.x * blockDim.x + threadIdx.x;
    if (i >= NBATCH * HW * C4) return;
    const int c4 = i % C4;
    const int px = (i / C4) % HW;
    const int n = i / (C4 * HW);
    const int c0 = 4 * c4;
    float inv[4], sh[4], v[4];
#pragma unroll
    for (int c = 0; c < 4; ++c) {
        const float m = ssum[c0 + c] * invM;
        inv[c] = g[c0 + c] / sqrtf(ssq[c0 + c] * invM - m * m + 1e-5f);
        sh[c] = be[c0 + c] - m * inv[c];
        v[c] = 0.0f;
    }
    const size_t ybase = ((size_t)n * HW + px) * C + c0;
    const size_t tstride = (size_t)NBATCH * HW * C;
    const int pyy = px / W, pxx = px % W;
    const size_t obase = (size_t)n * OSTR + ((pyy + 1) * (W + 2) + pxx + 1) * C + c0;
    const size_t ot = (size_t)NBATCH * OSTR;
#pragma unroll
    for (int t = 0; t < T_STEPS; ++t) {
        const float4 q = *(const float4*)&y[t * tstride + ybase];
        const float* qf = (const float*)&q;
        uint32_t pk = 0;
#pragma unroll
        for (int c = 0; c < 4; ++c) {
            const float z = qf[c] * inv[c] + sh[c];
            v[c] += (z - v[c]) * 0.5f;
            if (v[c] >= 1.0f) { v[c] = 0.0f; pk |= 1u << (8 * c); }
        }
        *(uint32_t*)&s[t * ot + obase] = pk;
    }
}

// BN+LIF + 2x2 max-pool (OR of spikes): y NHWC -> padded u8 (4 ch x 4 px/thread).
template <int C, int H, int W>
__global__ void bnlifpool_pad_kernel(const float* __restrict__ y,
                                     const float* __restrict__ ssum,
                                     const float* __restrict__ ssq,
                                     const float* __restrict__ g,
                                     const float* __restrict__ be,
                                     uint8_t* __restrict__ s, float invM) {
    constexpr int C4 = C / 4;
    constexpr int PH = H / 2, PW = W / 2;
    constexpr int OSTR = (PH + 2) * (PW + 2) * C;
    const int i = blockIdx.x * blockDim.x + threadIdx.x;
    if (i >= NBATCH * PH * PW * C4) return;
    const int c4 = i % C4;
    const int pw = (i / C4) % PW;
    const int ph = (i / (C4 * PW)) % PH;
    const int n = i / (C4 * PW * PH);
    const int c0 = 4 * c4;
    float inv[4], sh[4], v[4][4];
#pragma unroll
    for (int c = 0; c < 4; ++c) {
        const float m = ssum[c0 + c] * invM;
        inv[c] = g[c0 + c] / sqrtf(ssq[c0 + c] * invM - m * m + 1e-5f);
        sh[c] = be[c0 + c] - m * inv[c];
#pragma unroll
        for (int p = 0; p < 4; ++p) v[p][c] = 0.0f;
    }
    const size_t base = (((size_t)n * H + 2 * ph) * W + 2 * pw) * C + c0;
    const size_t tstride = (size_t)NBATCH * H * W * C;
    const size_t obase = (size_t)n * OSTR + ((ph + 1) * (PW + 2) + pw + 1) * C + c0;
    const size_t ot = (size_t)NBATCH * OSTR;
#pragma unroll
    for (int t = 0; t < T_STEPS; ++t) {
        const float* yt = y + t * tstride + base;
        float4 q[4];
        q[0] = *(const float4*)&yt[0];
        q[1] = *(const float4*)&yt[C];
        q[2] = *(const float4*)&yt[(size_t)W * C];
        q[3] = *(const float4*)&yt[(size_t)W * C + C];
        uint32_t pk = 0;
#pragma unroll
        for (int p = 0; p < 4; ++p) {
            const float* qf = (const float*)&q[p];
#pragma unroll
            for (int c = 0; c < 4; ++c) {
                const float z = qf[c] * inv[c] + sh[c];
                v[p][c] += (z - v[p][c]) * 0.5f;
                if (v[p][c] >= 1.0f) { v[p][c] = 0.0f; pk |= 1u << (8 * c); }
            }
        }
        *(uint32_t*)&s[t * ot + obase] = pk;
    }
}

// fc1 as MFMA GEMM.
__global__ __launch_bounds__(256) void fc1_mfma_kernel(
    const uint8_t* __restrict__ f, const uint16_t* __restrict__ wfc,
    const float* __restrict__ b, float* __restrict__ h)
{
    __shared__ __align__(16) uint16_t A[16 * 2056];
    const int tid = threadIdx.x;
    const int lane = tid & 63, wav = tid >> 6;
    const int col = lane & 15, quad = lane >> 4;
    const int r0 = blockIdx.x * 16;

    {
        const int row = tid >> 4, px = tid & 15;
        const int py = px >> 2, pxx = px & 3;
        const uint8_t* src = f + (size_t)(r0 + row) * 4608
                             + ((py + 1) * 6 + pxx + 1) * 128;
        uint32_t* dst = (uint32_t*)&A[row * 2056 + px * 128];
#pragma unroll
        for (int i = 0; i < 8; ++i) {
            const uint4 v = ((const uint4*)src)[i];
            dst[8 * i + 0] = ((v.x & 1u) | (((v.x >> 8) & 1u) << 16)) * 0x3F80u;
            dst[8 * i + 1] = (((v.x >> 16) & 1u) | (((v.x >> 24) & 1u) << 16)) * 0x3F80u;
            dst[8 * i + 2] = ((v.y & 1u) | (((v.y >> 8) & 1u) << 16)) * 0x3F80u;
            dst[8 * i + 3] = (((v.y >> 16) & 1u) | (((v.y >> 24) & 1u) << 16)) * 0x3F80u;
            dst[8 * i + 4] = ((v.z & 1u) | (((v.z >> 8) & 1u) << 16)) * 0x3F80u;
            dst[8 * i + 5] = (((v.z >> 16) & 1u) | (((v.z >> 24) & 1u) << 16)) * 0x3F80u;
            dst[8 * i + 6] = ((v.w & 1u) | (((v.w >> 8) & 1u) << 16)) * 0x3F80u;
            dst[8 * i + 7] = (((v.w >> 16) & 1u) | (((v.w >> 24) & 1u) << 16)) * 0x3F80u;
        }
    }
    __syncthreads();

    const int coblk = blockIdx.y * 4 + wav;
    const uint16_t* wbase = wfc + (size_t)coblk * 64 * 1664 + col * 104 + quad * 8;
    f32x4 acc = (f32x4)0.0f;

    auto loadB = [&](short8 (&buf)[3], int kc) {
        const uint16_t* p = wbase + kc * 1664;
        buf[0] = *(const short8*)p;
        buf[1] = *(const short8*)(p + 32);
        buf[2] = *(const short8*)(p + 64);
    };
    auto step = [&](short8 (&buf)[3], int kc) {
        const short8 a = *(const short8*)&A[col * 2056 + kc * 32 + quad * 8];
        acc = __builtin_amdgcn_mfma_f32_16x16x32_bf16(a, buf[0], acc, 0, 0, 0);
        acc = __builtin_amdgcn_mfma_f32_16x16x32_bf16(a, buf[1], acc, 0, 0, 0);
        acc = __builtin_amdgcn_mfma_f32_16x16x32_bf16(a, buf[2], acc, 0, 0, 0);
    };

    short8 bA[3], bB[3];
    loadB(bA, 0);
#pragma unroll 1
    for (int kc = 0; kc + 2 <= 64; kc += 2) {
        loadB(bB, kc + 1);
        step(bA, kc);
        if (kc + 2 < 64) loadB(bA, kc + 2);
        step(bB, kc + 1);
    }

    const int o = coblk * 16 + col;
    const float bv = b[o];
#pragma unroll
    for (int r = 0; r < 4; ++r)
        h[(size_t)(r0 + quad * 4 + r) * 128 + o] = acc[r] + bv;
}

// LIF over T for fc1 outputs.
__global__ void lif_fc_kernel(const float* __restrict__ h,
                              uint8_t* __restrict__ s, int NF) {
    const int i = blockIdx.x * blockDim.x + threadIdx.x;
    if (i >= NF) return;
    float v = 0.0f;
#pragma unroll
    for (int t = 0; t < T_STEPS; ++t) {
        const float z = h[(size_t)t * NF + i];
        v += (z - v) * 0.5f;
        const float sp = (v >= 1.0f) ? 1.0f : 0.0f;
        s[(size_t)t * NF + i] = (uint8_t)sp;
        v *= (1.0f - sp);
    }
}

// fc2 + LIF + mean over T.
__global__ void fc2_kernel(const uint8_t* __restrict__ sh,
                           const float* __restrict__ w,
                           const float* __restrict__ b,
                           float* __restrict__ out) {
    const int i = blockIdx.x * blockDim.x + threadIdx.x;
    if (i >= NBATCH * 10) return;
    const int k = i % 10;
    const int n = i / 10;
    float v = 0.0f, acc = 0.0f;
    for (int t = 0; t < T_STEPS; ++t) {
        const uint8_t* row = sh + ((size_t)t * NBATCH + n) * 128;
        float z = b[k];
        for (int o = 0; o < 128; ++o)
            z += (float)row[o] * w[k * 128 + o];
        v += (z - v) * 0.5f;
        const float sp = (v >= 1.0f) ? 1.0f : 0.0f;
        acc += sp;
        v *= (1.0f - sp);
    }
    out[i] = acc * (1.0f / T_STEPS);
}

extern "C" void kernel_launch(void* const* d_in, const int* in_sizes, int n_in,
                              void* d_out, int out_size, void* d_ws, size_t ws_size,
                              hipStream_t stream) {
    const float* x   = (const float*)d_in[0];
    const float* W1  = (const float*)d_in[1];
    const float* Bi1 = (const float*)d_in[2];
    const float* G1  = (const float*)d_in[3];
    const float* BE1 = (const float*)d_in[4];
    const float* W2  = (const float*)d_in[5];
    const float* Bi2 = (const float*)d_in[6];
    const float* G2  = (const float*)d_in[7];
    const float* BE2 = (const float*)d_in[8];
    const float* W3  = (const float*)d_in[9];
    const float* Bi3 = (const float*)d_in[10];
    const float* G3  = (const float*)d_in[11];
    const float* BE3 = (const float*)d_in[12];
    const float* W4  = (const float*)d_in[13];
    const float* Bi4 = (const float*)d_in[14];
    const float* G4  = (const float*)d_in[15];
    const float* BE4 = (const float*)d_in[16];
    const float* W5  = (const float*)d_in[17];
    const float* Bi5 = (const float*)d_in[18];
    const float* G5  = (const float*)d_in[19];
    const float* BE5 = (const float*)d_in[20];
    const float* W6  = (const float*)d_in[21];
    const float* Bi6 = (const float*)d_in[22];
    const float* G6  = (const float*)d_in[23];
    const float* BE6 = (const float*)d_in[24];
    const float* FC1W = (const float*)d_in[25];
    const float* FC1B = (const float*)d_in[26];
    const float* FC2W = (const float*)d_in[27];
    const float* FC2B = (const float*)d_in[28];

    // ---- workspace layout (≈176 MiB) ----
    uint8_t* ws = (uint8_t*)d_ws;
    float*   Y  = (float*)ws;                         // 134,217,728 B
    const size_t SOFF = 134217728;
    uint8_t* S1 = ws + SOFF;                          // 37,879,808
    uint8_t* S2 = ws + SOFF;                          // 10,616,832 (alias; S1 dead)
    uint8_t* S3 = ws + SOFF + 10616832;               // 21,233,664
    uint8_t* S4 = ws + SOFF;                          //  6,553,600 (S2 dead)
    uint8_t* S5 = ws + SOFF + 6553600;                // 13,107,200 (S3 dead)
    uint8_t* S6 = ws + SOFF + 19660800;               //  4,718,592
    float*   stats = (float*)(ws + SOFF + 37879808);  // 8 KB
    float*   h     = (float*)(ws + SOFF + 37879808 + 8192);      // 524,288
    uint8_t* shb   = ws + SOFF + 37879808 + 8192 + 524288;       // 131,072
    uint16_t* Wp   = (uint16_t*)(shb + 131072);
    uint16_t* Wp2p = Wp;
    uint16_t* Wp3p = Wp + 29952;
    uint16_t* Wp4p = Wp + 89856;
    uint16_t* Wp5p = Wp + 209664;
    uint16_t* Wp6p = Wp + 449280;
    uint16_t* Wfc1 = Wp + 928512;

    prep_all_kernel<<<(549376 + 255) / 256, 256, 0, stream>>>(
        W2, W3, W4, W5, W6, FC1W, Wp2p, Wp3p, Wp4p, Wp5p, Wp6p, Wfc1, stats);
    border_all_kernel<<<(5177344 + 255) / 256, 256, 0, stream>>>(S1, S2, S3, S4, S5, S6);

    const int TN = T_STEPS * NBATCH;  // 1024

    // ---- layer 1: conv(3->32) over N only (T-invariant), BN, LIF ----
    {
        conv1_kernel<<<dim3(NBATCH, 4), 256, 0, stream>>>(x, W1, Bi1, Y,
                                                          stats + 0, stats + 128);
        bnlif1_pad_kernel<<<(NBATCH * 1024 * 8) / 256, 256, 0, stream>>>(
            Y, stats + 0, stats + 128, G1, BE1, S1, 1.0f / 131072.0f);
    }
    // ---- layer 2: conv(32->32) 32x32, ROWS=8 (27.5KB LDS, 5 blk/CU) ----
    {
        conv_mfma_kernel<32, 32, 32, 32, 8, 1, 2, 1><<<dim3(TN * 4, 1), 256, 0, stream>>>(
            S1, Wp2p, Bi2, Y, stats + 256, stats + 384);
        bnlifpool_pad_kernel<32, 32, 32><<<(NBATCH * 16 * 16 * 8) / 256, 256, 0, stream>>>(
            Y, stats + 256, stats + 384, G2, BE2, S2, 1.0f / (1024.0f * 1024.0f));
    }
    // ---- layer 3: conv(32->64) 16x16, IMPB=1 (25.9KB, 6 blk/CU) ----
    {
        conv_mfma_kernel<32, 64, 16, 16, 16, 1, 2, 1><<<dim3(TN, 2), 256, 0, stream>>>(
            S2, Wp3p, Bi3, Y, stats + 512, stats + 640);
        bnlif_pad_kernel<64, 16, 16><<<(NBATCH * 256 * 16) / 256, 256, 0, stream>>>(
            Y, stats + 512, stats + 640, G3, BE3, S3, 1.0f / (1024.0f * 256.0f));
    }
    // ---- layer 4: conv(64->64) 16x16, ROWS=8, K-split 2 (25.9KB, 6 blk/CU) ----
    {
        conv_mfma_kernel<64, 64, 16, 16, 8, 1, 2, 2><<<dim3(TN * 2, 2), 256, 0, stream>>>(
            S3, Wp4p, Bi4, Y, stats + 768, stats + 896);
        bnlifpool_pad_kernel<64, 16, 16><<<(NBATCH * 8 * 8 * 16) / 256, 256, 0, stream>>>(
            Y, stats + 768, stats + 896, G4, BE4, S4, 1.0f / (1024.0f * 256.0f));
    }
    // ---- layer 5: conv(64->128) 8x8, 2 img/block, 32 co/block, K-split 2 ----
    {
        conv_mfma_kernel<64, 128, 8, 8, 8, 2, 2, 2><<<dim3(TN / 2, 4), 256, 0, stream>>>(
            S4, Wp5p, Bi5, Y, stats + 1024, stats + 1152);
        bnlif_pad_kernel<128, 8, 8><<<(NBATCH * 64 * 32) / 256, 256, 0, stream>>>(
            Y, stats + 1024, stats + 1152, G5, BE5, S5, 1.0f / (1024.0f * 64.0f));
    }
    // ---- layer 6: conv(128->128) 8x8, 2 img/block, 32 co/block, K-split 4 ----
    {
        conv_mfma_kernel<128, 128, 8, 8, 8, 2, 2, 4><<<dim3(TN / 2, 4), 256, 0, stream>>>(
            S5, Wp6p, Bi6, Y, stats + 1280, stats + 1408);
        bnlifpool_pad_kernel<128, 8, 8><<<(NBATCH * 4 * 4 * 32) / 256, 256, 0, stream>>>(
            Y, stats + 1280, stats + 1408, G6, BE6, S6, 1.0f / (1024.0f * 64.0f));
    }
    // ---- fc1 (2048->128) via MFMA + LIF ----
    fc1_mfma_kernel<<<dim3(64, 2), 256, 0, stream>>>(S6, Wfc1, FC1B, h);
    lif_fc_kernel<<<(NBATCH * 128 + 255) / 256, 256, 0, stream>>>(h, shb, NBATCH * 128);
    // ---- fc2 (128->10) + LIF + mean ----
    fc2_kernel<<<(NBATCH * 10 + 255) / 256, 256, 0, stream>>>(shb, FC2W, FC2B, (float*)d_out);
}

// Round 15
// 620.945 us; speedup vs baseline: 1.0289x; 1.0289x over previous
//
#include <hip/hip_runtime.h>
#include <stdint.h>

// ---------------------------------------------------------------------------
// EnhancedSNNCifar: T=8 SNN forward.
// R15: selective revert of R14. Keep conv2 ROWS=8 (27.5KB LDS, 5 blk/CU —
//      occupancy up, neutral-positive; conv2 is byte-floor-bound at 132MB Y
//      write). Revert conv3 to IMPB=2/NCO=2 (A staged ONCE for both co
//      groups; R14's IMPB=1 doubled A fetches) and conv4 to ROWS=16/KSPLIT=2
//      (R14's ROWS=8 doubled per-block B traffic). Math identical -> absmax 0.
// ---------------------------------------------------------------------------

#define T_STEPS 8
#define NBATCH 128

typedef __attribute__((ext_vector_type(8))) short short8;
typedef __attribute__((ext_vector_type(4))) float f32x4;

__device__ __forceinline__ uint16_t f2bf(float f) {
    uint32_t x = __float_as_uint(f);
    uint32_t r = x + 0x7FFFu + ((x >> 16) & 1u);
    return (uint16_t)(r >> 16);
}
__device__ __forceinline__ float bf2f(uint16_t h) {
    return __uint_as_float(((uint32_t)h) << 16);
}

// ---------------------------------------------------------------------------
// Merged weight prep (5 convs + fc1) + stats zeroing, triple-bf16-split.
// ---------------------------------------------------------------------------
__device__ __forceinline__ void tsplit(float v, uint16_t& h1, uint16_t& h2, uint16_t& h3) {
    h1 = f2bf(v);
    const float r1 = v - bf2f(h1);
    h2 = f2bf(r1);
    const float r2 = r1 - bf2f(h2);
    h3 = f2bf(r2);
}

__device__ __forceinline__ void prep_conv_one(const float* __restrict__ w,
                                              uint16_t* __restrict__ wp, int i, int CIN) {
    const int KC = CIN >> 5;
    const int sh = i % 9;
    const int ci = (i / 9) % CIN;
    const int co = i / (9 * CIN);
    uint16_t h1, h2, h3;
    tsplit(w[i], h1, h2, h3);
    uint16_t* base = wp + (size_t)((co >> 4) * KC + (ci >> 5)) * 14976
                        + sh * 1664 + (co & 15) * 104 + (ci & 31);
    base[0] = h1;
    base[32] = h2;
    base[64] = h3;
}

__device__ __forceinline__ void prep_fc1_one(const float* __restrict__ w,
                                             uint16_t* __restrict__ wp, int i) {
    const int kp = i & 2047;
    const int o = i >> 11;
    const int px = kp >> 7, c = kp & 127;
    uint16_t h1, h2, h3;
    tsplit(w[o * 2048 + c * 16 + px], h1, h2, h3);
    uint16_t* base = wp + (size_t)((o >> 4) * 64 + (kp >> 5)) * 1664
                        + (o & 15) * 104 + (kp & 31);
    base[0] = h1;
    base[32] = h2;
    base[64] = h3;
}

__global__ void prep_all_kernel(const float* __restrict__ W2, const float* __restrict__ W3,
                                const float* __restrict__ W4, const float* __restrict__ W5,
                                const float* __restrict__ W6, const float* __restrict__ F1,
                                uint16_t* __restrict__ P2, uint16_t* __restrict__ P3,
                                uint16_t* __restrict__ P4, uint16_t* __restrict__ P5,
                                uint16_t* __restrict__ P6, uint16_t* __restrict__ PF,
                                float* __restrict__ stats) {
    int i = blockIdx.x * blockDim.x + threadIdx.x;
    if (i < 1536) { stats[i] = 0.0f; return; }
    i -= 1536;
    if (i < 9216) { prep_conv_one(W2, P2, i, 32); return; }
    i -= 9216;
    if (i < 18432) { prep_conv_one(W3, P3, i, 32); return; }
    i -= 18432;
    if (i < 36864) { prep_conv_one(W4, P4, i, 64); return; }
    i -= 36864;
    if (i < 73728) { prep_conv_one(W5, P5, i, 64); return; }
    i -= 73728;
    if (i < 147456) { prep_conv_one(W6, P6, i, 128); return; }
    i -= 147456;
    if (i < 262144) prep_fc1_one(F1, PF, i);
}

// Merged halo-border zeroing for all 6 u8 spike arrays (4 ch per thread).
__global__ void border_all_kernel(uint8_t* S1, uint8_t* S2, uint8_t* S3,
                                  uint8_t* S4, uint8_t* S5, uint8_t* S6) {
    int i = blockIdx.x * blockDim.x + threadIdx.x;
    uint8_t* s;
    int C, HP, WPP;
    if (i < 1081344) { s = S1; C = 32; HP = 34; WPP = 34; }
    else if ((i -= 1081344) < 557056) { s = S2; C = 32; HP = 18; WPP = 18; }
    else if ((i -= 557056) < 1114112) { s = S3; C = 64; HP = 18; WPP = 18; }
    else if ((i -= 1114112) < 589824) { s = S4; C = 64; HP = 10; WPP = 10; }
    else if ((i -= 589824) < 1179648) { s = S5; C = 128; HP = 10; WPP = 10; }
    else if ((i -= 1179648) < 655360) { s = S6; C = 128; HP = 6; WPP = 6; }
    else return;
    const int C4 = C >> 2;
    const int NB = 2 * WPP + 2 * (HP - 2);
    const int c4 = i % C4;
    const int b = (i / C4) % NB;
    const int img = i / (C4 * NB);
    int py, px;
    if (b < WPP) { py = 0; px = b; }
    else if (b < 2 * WPP) { py = HP - 1; px = b - WPP; }
    else { const int r = b - 2 * WPP; py = 1 + (r >> 1); px = (r & 1) ? (WPP - 1) : 0; }
    *(uint32_t*)&s[(size_t)img * (HP * WPP * C) + (py * WPP + px) * C + 4 * c4] = 0u;
}

// ---------------------------------------------------------------------------
// conv1 (3->32, 32x32, fp32 NCHW input): block 256 = 8 strips x 32 co.
// ---------------------------------------------------------------------------
__global__ __launch_bounds__(256) void conv1_kernel(
    const float* __restrict__ x, const float* __restrict__ w,
    const float* __restrict__ bias, float* __restrict__ y,
    float* __restrict__ ssum, float* __restrict__ ssq)
{
    __shared__ float tile[3][10][34];
    __shared__ float bnl[64];
    const int tid = threadIdx.x;
    const int m = blockIdx.x;
    const int y0 = blockIdx.y * 8;
    const int co = tid & 31;
    const int strip = tid >> 5;

    if (tid < 64) bnl[tid] = 0.0f;
    for (int i = tid; i < 3 * 10 * 34; i += 256) ((float*)tile)[i] = 0.0f;
    __syncthreads();

    {
        const int gy0 = (y0 == 0) ? 0 : y0 - 1;
        const int gy1 = (y0 + 8 > 31) ? 31 : y0 + 8;
        const int nrows = gy1 - gy0 + 1;
        for (int i = tid; i < 3 * nrows * 32; i += 256) {
            const int gx = i & 31;
            const int r = (i >> 5) % nrows;
            const int ci = i / (32 * nrows);
            const int gy = gy0 + r;
            tile[ci][gy - y0 + 1][gx + 1] =
                x[((size_t)m * 3 + ci) * 1024 + gy * 32 + gx];
        }
    }
    __syncthreads();

    float wr[27];
#pragma unroll
    for (int j = 0; j < 27; ++j) wr[j] = w[co * 27 + j];
    const float bv = bias[co];

    float lsum = 0.0f, lsq = 0.0f;
#pragma unroll
    for (int g = 0; g < 8; ++g) {
        float s[3][3][6];
#pragma unroll
        for (int ci = 0; ci < 3; ++ci)
#pragma unroll
            for (int ky = 0; ky < 3; ++ky)
#pragma unroll
                for (int c = 0; c < 6; ++c)
                    s[ci][ky][c] = tile[ci][g + ky][strip * 4 + c];
#pragma unroll
        for (int r = 0; r < 4; ++r) {
            float acc = bv;
#pragma unroll
            for (int ci = 0; ci < 3; ++ci)
#pragma unroll
                for (int ky = 0; ky < 3; ++ky)
#pragma unroll
                    for (int kx = 0; kx < 3; ++kx)
                        acc += s[ci][ky][r + kx] * wr[ci * 9 + ky * 3 + kx];
            const int lx = strip * 4 + r;
            y[(((size_t)m * 1024) + (y0 + g) * 32 + lx) * 32 + co] = acc;
            lsum += acc;
            lsq += acc * acc;
        }
    }
    atomicAdd(&bnl[co], lsum);
    atomicAdd(&bnl[32 + co], lsq);
    __syncthreads();
    if (tid < 32) atomicAdd(&ssum[tid], bnl[tid]);
    else if (tid < 64) atomicAdd(&ssq[tid - 32], bnl[tid]);
}

// ---------------------------------------------------------------------------
// MFMA spike conv. in: padded u8 spikes [m][(H+2)(W+2)][CIN] (halo zero).
// grid = ((M/IMPB)*(H/ROWS), COUT/(16*NCO)), block 256 (4 waves).
// ---------------------------------------------------------------------------
template <int CIN, int COUT, int H, int W, int ROWS, int IMPB, int NCO, int KSPLIT>
__global__ __launch_bounds__(256) void conv_mfma_kernel(
    const uint8_t* __restrict__ in, const uint16_t* __restrict__ wp,
    const float* __restrict__ bias, float* __restrict__ y,
    float* __restrict__ ssum, float* __restrict__ ssq)
{
    constexpr int KC = CIN / 32;
    constexpr int WPP = W + 2;
    constexpr int HW = H * W;
    constexpr int PXU16 = CIN + 8;
    constexpr int ISTR_B = (H + 2) * WPP * CIN;
    constexpr int RB = H / ROWS;
    constexpr int NSTRIP = IMPB * ROWS * W / 16;
    constexpr int MSPLIT = 4 / KSPLIT;
    constexpr int SPW = NSTRIP / MSPLIT;
    constexpr int TILE_U16 = IMPB * (ROWS + 2) * WPP * PXU16;
    constexpr int TILE_B = IMPB * (ROWS + 2) * WPP * CIN;
    constexpr int NIT = KC * 9;
    constexpr int ITW = NIT / KSPLIT;
    constexpr int CS = NCO * 16 + 1;
    static_assert(IMPB == 1 || ROWS == H, "impb needs full-image tiles");
    static_assert(NSTRIP % MSPLIT == 0 && NSTRIP % 4 == 0, "strips");
    static_assert(NIT % KSPLIT == 0, "ksplit");
    static_assert(TILE_B % 16 == 0, "tile u8 16B");
    static_assert(KSPLIT == 1 || TILE_U16 * 2 >= NSTRIP * 16 * CS * 4, "C fits");

    __shared__ __align__(16) uint16_t sp[TILE_U16];
    __shared__ float bn[NCO * 32];

    const int tid = threadIdx.x;
    const int lane = tid & 63;
    const int wav = tid >> 6;
    const int kg = wav / MSPLIT;
    const int mg = wav - kg * MSPLIT;
    const int col = lane & 15;
    const int quad = lane >> 4;

    const int m0 = (blockIdx.x / RB) * IMPB;
    const int ybase = (blockIdx.x % RB) * ROWS;

    if (tid < NCO * 32) bn[tid] = 0.0f;

    // ---- stage spike tile: u8 -> bf16 expand ----
    {
        const uint8_t* src = in + (size_t)m0 * ISTR_B + (size_t)ybase * WPP * CIN;
        for (int i = tid; i < TILE_B / 16; i += 256) {
            const uint4 v = ((const uint4*)src)[i];
            const int b = i * 16;
            const int px = b / CIN;
            const int ci = b - px * CIN;
            uint32_t* d = (uint32_t*)&sp[px * PXU16 + ci];
            d[0] = ((v.x & 1u) | (((v.x >> 8) & 1u) << 16)) * 0x3F80u;
            d[1] = (((v.x >> 16) & 1u) | (((v.x >> 24) & 1u) << 16)) * 0x3F80u;
            d[2] = ((v.y & 1u) | (((v.y >> 8) & 1u) << 16)) * 0x3F80u;
            d[3] = (((v.y >> 16) & 1u) | (((v.y >> 24) & 1u) << 16)) * 0x3F80u;
            d[4] = ((v.z & 1u) | (((v.z >> 8) & 1u) << 16)) * 0x3F80u;
            d[5] = (((v.z >> 16) & 1u) | (((v.z >> 24) & 1u) << 16)) * 0x3F80u;
            d[6] = ((v.w & 1u) | (((v.w >> 8) & 1u) << 16)) * 0x3F80u;
            d[7] = (((v.w >> 16) & 1u) | (((v.w >> 24) & 1u) << 16)) * 0x3F80u;
        }
    }
    __syncthreads();

    int abase[SPW];
#pragma unroll
    for (int s = 0; s < SPW; ++s) {
        const int p = (mg * SPW + s) * 16 + col;
        const int img = p / (ROWS * W);
        const int rem = p % (ROWS * W);
        abase[s] = ((img * (ROWS + 2) + rem / W) * WPP + rem % W) * PXU16 + quad * 8;
    }

    f32x4 acc[SPW][NCO];
#pragma unroll
    for (int s = 0; s < SPW; ++s)
#pragma unroll
        for (int j = 0; j < NCO; ++j) acc[s][j] = (f32x4)0.0f;

    const uint16_t* wbase = wp + ((size_t)blockIdx.y * NCO * KC) * 14976
                               + col * 104 + quad * 8;

    auto loadB = [&](short8 (&buf)[NCO][3], int it) {
        const int kc = it / 9, sh = it - kc * 9;
#pragma unroll
        for (int j = 0; j < NCO; ++j) {
            const uint16_t* p = wbase + (size_t)(j * KC + kc) * 14976 + sh * 1664;
            buf[j][0] = *(const short8*)p;
            buf[j][1] = *(const short8*)(p + 32);
            buf[j][2] = *(const short8*)(p + 64);
        }
    };
    auto mfmaStep = [&](short8 (&buf)[NCO][3], int it) {
        const int kc = it / 9, sh = it - kc * 9;
        const int dy = sh / 3, dx = sh - dy * 3;
        const int shoff = (dy * WPP + dx) * PXU16 + kc * 32;
#pragma unroll
        for (int s = 0; s < SPW; ++s) {
            const short8 a = *(const short8*)&sp[abase[s] + shoff];
#pragma unroll
            for (int j = 0; j < NCO; ++j) {
                f32x4 t = acc[s][j];
                t = __builtin_amdgcn_mfma_f32_16x16x32_bf16(a, buf[j][0], t, 0, 0, 0);
                t = __builtin_amdgcn_mfma_f32_16x16x32_bf16(a, buf[j][1], t, 0, 0, 0);
                t = __builtin_amdgcn_mfma_f32_16x16x32_bf16(a, buf[j][2], t, 0, 0, 0);
                acc[s][j] = t;
            }
        }
    };

    short8 bufA[NCO][3], bufB[NCO][3];
    const int it0 = kg * ITW, it1 = it0 + ITW;
    loadB(bufA, it0);
    int it = it0;
#pragma unroll 1
    for (; it + 2 <= it1; it += 2) {
        loadB(bufB, it + 1);
        mfmaStep(bufA, it);
        if (it + 2 < it1) loadB(bufA, it + 2);
        mfmaStep(bufB, it + 1);
    }
    if (it < it1) mfmaStep(bufA, it);

    float bv[NCO];
#pragma unroll
    for (int j = 0; j < NCO; ++j) bv[j] = bias[(blockIdx.y * NCO + j) * 16 + col];

    if constexpr (KSPLIT == 1) {
#pragma unroll
        for (int s = 0; s < SPW; ++s) {
            const int pb_ = (mg * SPW + s) * 16 + quad * 4;
            float sum[NCO], sq[NCO];
#pragma unroll
            for (int j = 0; j < NCO; ++j) { sum[j] = 0.0f; sq[j] = 0.0f; }
#pragma unroll
            for (int r = 0; r < 4; ++r) {
                const int p = pb_ + r;
                const int img = p / (ROWS * W);
                const int pxim = p % (ROWS * W) + ybase * W;
                float* yp = &y[((size_t)(m0 + img) * HW + pxim) * COUT
                               + blockIdx.y * NCO * 16 + col];
#pragma unroll
                for (int j = 0; j < NCO; ++j) {   // j innermost: 128B line merge
                    const float v = acc[s][j][r] + bv[j];
                    yp[j * 16] = v;
                    sum[j] += v;
                    sq[j] += v * v;
                }
            }
#pragma unroll
            for (int j = 0; j < NCO; ++j) {
                float su = sum[j], s2 = sq[j];
                su += __shfl_xor(su, 16, 64);
                su += __shfl_xor(su, 32, 64);
                s2 += __shfl_xor(s2, 16, 64);
                s2 += __shfl_xor(s2, 32, 64);
                if (quad == 0) {
                    atomicAdd(&bn[j * 32 + col], su);
                    atomicAdd(&bn[j * 32 + 16 + col], s2);
                }
            }
        }
    } else {
        float* Csh = (float*)sp;
        __syncthreads();
        if (kg == 0) {
#pragma unroll
            for (int s = 0; s < SPW; ++s)
#pragma unroll
                for (int j = 0; j < NCO; ++j)
#pragma unroll
                    for (int r = 0; r < 4; ++r)
                        Csh[((mg * SPW + s) * 16 + quad * 4 + r) * CS + j * 16 + col]
                            = acc[s][j][r];
        }
        __syncthreads();
#pragma unroll
        for (int k = 1; k < KSPLIT; ++k) {
            if (kg == k) {
#pragma unroll
                for (int s = 0; s < SPW; ++s)
#pragma unroll
                    for (int j = 0; j < NCO; ++j)
#pragma unroll
                        for (int r = 0; r < 4; ++r)
                            Csh[((mg * SPW + s) * 16 + quad * 4 + r) * CS + j * 16 + col]
                                += acc[s][j][r];
            }
            __syncthreads();
        }
        constexpr int ES = NSTRIP / 4;
#pragma unroll
        for (int s2i = 0; s2i < ES; ++s2i) {
            const int gs = wav * ES + s2i;
            float sum[NCO], sq[NCO];
#pragma unroll
            for (int j = 0; j < NCO; ++j) { sum[j] = 0.0f; sq[j] = 0.0f; }
#pragma unroll
            for (int r = 0; r < 4; ++r) {
                const int p = gs * 16 + quad * 4 + r;
                const int img = p / (ROWS * W);
                const int pxim = p % (ROWS * W) + ybase * W;
                float* yp = &y[((size_t)(m0 + img) * HW + pxim) * COUT
                               + blockIdx.y * NCO * 16 + col];
#pragma unroll
                for (int j = 0; j < NCO; ++j) {
                    const float v = Csh[p * CS + j * 16 + col] + bv[j];
                    yp[j * 16] = v;
                    sum[j] += v;
                    sq[j] += v * v;
                }
            }
#pragma unroll
            for (int j = 0; j < NCO; ++j) {
                float su = sum[j], s2 = sq[j];
                su += __shfl_xor(su, 16, 64);
                su += __shfl_xor(su, 32, 64);
                s2 += __shfl_xor(s2, 16, 64);
                s2 += __shfl_xor(s2, 32, 64);
                if (quad == 0) {
                    atomicAdd(&bn[j * 32 + col], su);
                    atomicAdd(&bn[j * 32 + 16 + col], s2);
                }
            }
        }
    }
    __syncthreads();
    if (tid < NCO * 32) {
        const int j = tid >> 5, r = tid & 31;
        const int co0 = (blockIdx.y * NCO + j) * 16;
        if (r < 16) atomicAdd(&ssum[co0 + r], bn[j * 32 + r]);
        else atomicAdd(&ssq[co0 + r - 16], bn[j * 32 + r]);
    }
}

// Layer-1 BN+LIF: y NHWC [N][1024][32] (T-invariant) -> padded u8 spikes.
__global__ void bnlif1_pad_kernel(const float* __restrict__ y,
                                  const float* __restrict__ ssum,
                                  const float* __restrict__ ssq,
                                  const float* __restrict__ g,
                                  const float* __restrict__ be,
                                  uint8_t* __restrict__ s, float invM) {
    constexpr int OSTR = 34 * 34 * 32;
    const int i = blockIdx.x * blockDim.x + threadIdx.x;
    if (i >= NBATCH * 1024 * 8) return;
    const int c4 = i & 7;
    const int px = (i >> 3) & 1023;
    const int n = i >> 13;
    const int c0 = 4 * c4;
    float z[4], v[4];
    const float4 q = *(const float4*)&y[((size_t)n * 1024 + px) * 32 + c0];
    const float* qf = (const float*)&q;
#pragma unroll
    for (int c = 0; c < 4; ++c) {
        const float m = ssum[c0 + c] * invM;
        const float inv = g[c0 + c] / sqrtf(ssq[c0 + c] * invM - m * m + 1e-5f);
        z[c] = qf[c] * inv + (be[c0 + c] - m * inv);
        v[c] = 0.0f;
    }
    const int pyy = px >> 5, pxx = px & 31;
    const size_t obase = (size_t)n * OSTR + ((pyy + 1) * 34 + pxx + 1) * 32 + c0;
    const size_t ot = (size_t)NBATCH * OSTR;
#pragma unroll
    for (int t = 0; t < T_STEPS; ++t) {
        uint32_t pk = 0;
#pragma unroll
        for (int c = 0; c < 4; ++c) {
            v[c] += (z[c] - v[c]) * 0.5f;
            if (v[c] >= 1.0f) { v[c] = 0.0f; pk |= 1u << (8 * c); }
        }
        *(uint32_t*)&s[t * ot + obase] = pk;
    }
}

// BN+LIF (no pool): y NHWC [T*N][HW][C] -> padded u8 spikes (4 ch/thread).
template <int C, int H, int W>
__global__ void bnlif_pad_kernel(const float* __restrict__ y,
                                 const float* __restrict__ ssum,
                                 const float* __restrict__ ssq,
                                 const float* __restrict__ g,
                                 const float* __restrict__ be,
                                 uint8_t* __restrict__ s, float invM) {
    constexpr int C4 = C / 4;
    constexpr int HW = H * W;
    constexpr int OSTR = (H + 2) * (W + 2) * C;
    const int i = blockIdx.x * blockDim.x + threadIdx.x;
    if (i >= NBATCH * HW * C4) return;
    const int c4 = i % C4;
    const int px = (i / C4) % HW;
    const int n = i / (C4 * HW);
    const int c0 = 4 * c4;
    float inv[4], sh[4], v[4];
#pragma unroll
    for (int c = 0; c < 4; ++c) {
        const float m = ssum[c0 + c] * invM;
        inv[c] = g[c0 + c] / sqrtf(ssq[c0 + c] * invM - m * m + 1e-5f);
        sh[c] = be[c0 + c] - m * inv[c];
        v[c] = 0.0f;
    }
    const size_t ybase = ((size_t)n * HW + px) * C + c0;
    const size_t tstride = (size_t)NBATCH * HW * C;
    const int pyy = px / W, pxx = px % W;
    const size_t obase = (size_t)n * OSTR + ((pyy + 1) * (W + 2) + pxx + 1) * C + c0;
    const size_t ot = (size_t)NBATCH * OSTR;
#pragma unroll
    for (int t = 0; t < T_STEPS; ++t) {
        const float4 q = *(const float4*)&y[t * tstride + ybase];
        const float* qf = (const float*)&q;
        uint32_t pk = 0;
#pragma unroll
        for (int c = 0; c < 4; ++c) {
            const float z = qf[c] * inv[c] + sh[c];
            v[c] += (z - v[c]) * 0.5f;
            if (v[c] >= 1.0f) { v[c] = 0.0f; pk |= 1u << (8 * c); }
        }
        *(uint32_t*)&s[t * ot + obase] = pk;
    }
}

// BN+LIF + 2x2 max-pool (OR of spikes): y NHWC -> padded u8 (4 ch x 4 px/thread).
template <int C, int H, int W>
__global__ void bnlifpool_pad_kernel(const float* __restrict__ y,
                                     const float* __restrict__ ssum,
                                     const float* __restrict__ ssq,
                                     const float* __restrict__ g,
                                     const float* __restrict__ be,
                                     uint8_t* __restrict__ s, float invM) {
    constexpr int C4 = C / 4;
    constexpr int PH = H / 2, PW = W / 2;
    constexpr int OSTR = (PH + 2) * (PW + 2) * C;
    const int i = blockIdx.x * blockDim.x + threadIdx.x;
    if (i >= NBATCH * PH * PW * C4) return;
    const int c4 = i % C4;
    const int pw = (i / C4) % PW;
    const int ph = (i / (C4 * PW)) % PH;
    const int n = i / (C4 * PW * PH);
    const int c0 = 4 * c4;
    float inv[4], sh[4], v[4][4];
#pragma unroll
    for (int c = 0; c < 4; ++c) {
        const float m = ssum[c0 + c] * invM;
        inv[c] = g[c0 + c] / sqrtf(ssq[c0 + c] * invM - m * m + 1e-5f);
        sh[c] = be[c0 + c] - m * inv[c];
#pragma unroll
        for (int p = 0; p < 4; ++p) v[p][c] = 0.0f;
    }
    const size_t base = (((size_t)n * H + 2 * ph) * W + 2 * pw) * C + c0;
    const size_t tstride = (size_t)NBATCH * H * W * C;
    const size_t obase = (size_t)n * OSTR + ((ph + 1) * (PW + 2) + pw + 1) * C + c0;
    const size_t ot = (size_t)NBATCH * OSTR;
#pragma unroll
    for (int t = 0; t < T_STEPS; ++t) {
        const float* yt = y + t * tstride + base;
        float4 q[4];
        q[0] = *(const float4*)&yt[0];
        q[1] = *(const float4*)&yt[C];
        q[2] = *(const float4*)&yt[(size_t)W * C];
        q[3] = *(const float4*)&yt[(size_t)W * C + C];
        uint32_t pk = 0;
#pragma unroll
        for (int p = 0; p < 4; ++p) {
            const float* qf = (const float*)&q[p];
#pragma unroll
            for (int c = 0; c < 4; ++c) {
                const float z = qf[c] * inv[c] + sh[c];
                v[p][c] += (z - v[p][c]) * 0.5f;
                if (v[p][c] >= 1.0f) { v[p][c] = 0.0f; pk |= 1u << (8 * c); }
            }
        }
        *(uint32_t*)&s[t * ot + obase] = pk;
    }
}

// fc1 as MFMA GEMM.
__global__ __launch_bounds__(256) void fc1_mfma_kernel(
    const uint8_t* __restrict__ f, const uint16_t* __restrict__ wfc,
    const float* __restrict__ b, float* __restrict__ h)
{
    __shared__ __align__(16) uint16_t A[16 * 2056];
    const int tid = threadIdx.x;
    const int lane = tid & 63, wav = tid >> 6;
    const int col = lane & 15, quad = lane >> 4;
    const int r0 = blockIdx.x * 16;

    {
        const int row = tid >> 4, px = tid & 15;
        const int py = px >> 2, pxx = px & 3;
        const uint8_t* src = f + (size_t)(r0 + row) * 4608
                             + ((py + 1) * 6 + pxx + 1) * 128;
        uint32_t* dst = (uint32_t*)&A[row * 2056 + px * 128];
#pragma unroll
        for (int i = 0; i < 8; ++i) {
            const uint4 v = ((const uint4*)src)[i];
            dst[8 * i + 0] = ((v.x & 1u) | (((v.x >> 8) & 1u) << 16)) * 0x3F80u;
            dst[8 * i + 1] = (((v.x >> 16) & 1u) | (((v.x >> 24) & 1u) << 16)) * 0x3F80u;
            dst[8 * i + 2] = ((v.y & 1u) | (((v.y >> 8) & 1u) << 16)) * 0x3F80u;
            dst[8 * i + 3] = (((v.y >> 16) & 1u) | (((v.y >> 24) & 1u) << 16)) * 0x3F80u;
            dst[8 * i + 4] = ((v.z & 1u) | (((v.z >> 8) & 1u) << 16)) * 0x3F80u;
            dst[8 * i + 5] = (((v.z >> 16) & 1u) | (((v.z >> 24) & 1u) << 16)) * 0x3F80u;
            dst[8 * i + 6] = ((v.w & 1u) | (((v.w >> 8) & 1u) << 16)) * 0x3F80u;
            dst[8 * i + 7] = (((v.w >> 16) & 1u) | (((v.w >> 24) & 1u) << 16)) * 0x3F80u;
        }
    }
    __syncthreads();

    const int coblk = blockIdx.y * 4 + wav;
    const uint16_t* wbase = wfc + (size_t)coblk * 64 * 1664 + col * 104 + quad * 8;
    f32x4 acc = (f32x4)0.0f;

    auto loadB = [&](short8 (&buf)[3], int kc) {
        const uint16_t* p = wbase + kc * 1664;
        buf[0] = *(const short8*)p;
        buf[1] = *(const short8*)(p + 32);
        buf[2] = *(const short8*)(p + 64);
    };
    auto step = [&](short8 (&buf)[3], int kc) {
        const short8 a = *(const short8*)&A[col * 2056 + kc * 32 + quad * 8];
        acc = __builtin_amdgcn_mfma_f32_16x16x32_bf16(a, buf[0], acc, 0, 0, 0);
        acc = __builtin_amdgcn_mfma_f32_16x16x32_bf16(a, buf[1], acc, 0, 0, 0);
        acc = __builtin_amdgcn_mfma_f32_16x16x32_bf16(a, buf[2], acc, 0, 0, 0);
    };

    short8 bA[3], bB[3];
    loadB(bA, 0);
#pragma unroll 1
    for (int kc = 0; kc + 2 <= 64; kc += 2) {
        loadB(bB, kc + 1);
        step(bA, kc);
        if (kc + 2 < 64) loadB(bA, kc + 2);
        step(bB, kc + 1);
    }

    const int o = coblk * 16 + col;
    const float bv = b[o];
#pragma unroll
    for (int r = 0; r < 4; ++r)
        h[(size_t)(r0 + quad * 4 + r) * 128 + o] = acc[r] + bv;
}

// LIF over T for fc1 outputs.
__global__ void lif_fc_kernel(const float* __restrict__ h,
                              uint8_t* __restrict__ s, int NF) {
    const int i = blockIdx.x * blockDim.x + threadIdx.x;
    if (i >= NF) return;
    float v = 0.0f;
#pragma unroll
    for (int t = 0; t < T_STEPS; ++t) {
        const float z = h[(size_t)t * NF + i];
        v += (z - v) * 0.5f;
        const float sp = (v >= 1.0f) ? 1.0f : 0.0f;
        s[(size_t)t * NF + i] = (uint8_t)sp;
        v *= (1.0f - sp);
    }
}

// fc2 + LIF + mean over T.
__global__ void fc2_kernel(const uint8_t* __restrict__ sh,
                           const float* __restrict__ w,
                           const float* __restrict__ b,
                           float* __restrict__ out) {
    const int i = blockIdx.x * blockDim.x + threadIdx.x;
    if (i >= NBATCH * 10) return;
    const int k = i % 10;
    const int n = i / 10;
    float v = 0.0f, acc = 0.0f;
    for (int t = 0; t < T_STEPS; ++t) {
        const uint8_t* row = sh + ((size_t)t * NBATCH + n) * 128;
        float z = b[k];
        for (int o = 0; o < 128; ++o)
            z += (float)row[o] * w[k * 128 + o];
        v += (z - v) * 0.5f;
        const float sp = (v >= 1.0f) ? 1.0f : 0.0f;
        acc += sp;
        v *= (1.0f - sp);
    }
    out[i] = acc * (1.0f / T_STEPS);
}

extern "C" void kernel_launch(void* const* d_in, const int* in_sizes, int n_in,
                              void* d_out, int out_size, void* d_ws, size_t ws_size,
                              hipStream_t stream) {
    const float* x   = (const float*)d_in[0];
    const float* W1  = (const float*)d_in[1];
    const float* Bi1 = (const float*)d_in[2];
    const float* G1  = (const float*)d_in[3];
    const float* BE1 = (const float*)d_in[4];
    const float* W2  = (const float*)d_in[5];
    const float* Bi2 = (const float*)d_in[6];
    const float* G2  = (const float*)d_in[7];
    const float* BE2 = (const float*)d_in[8];
    const float* W3  = (const float*)d_in[9];
    const float* Bi3 = (const float*)d_in[10];
    const float* G3  = (const float*)d_in[11];
    const float* BE3 = (const float*)d_in[12];
    const float* W4  = (const float*)d_in[13];
    const float* Bi4 = (const float*)d_in[14];
    const float* G4  = (const float*)d_in[15];
    const float* BE4 = (const float*)d_in[16];
    const float* W5  = (const float*)d_in[17];
    const float* Bi5 = (const float*)d_in[18];
    const float* G5  = (const float*)d_in[19];
    const float* BE5 = (const float*)d_in[20];
    const float* W6  = (const float*)d_in[21];
    const float* Bi6 = (const float*)d_in[22];
    const float* G6  = (const float*)d_in[23];
    const float* BE6 = (const float*)d_in[24];
    const float* FC1W = (const float*)d_in[25];
    const float* FC1B = (const float*)d_in[26];
    const float* FC2W = (const float*)d_in[27];
    const float* FC2B = (const float*)d_in[28];

    // ---- workspace layout (≈176 MiB) ----
    uint8_t* ws = (uint8_t*)d_ws;
    float*   Y  = (float*)ws;                         // 134,217,728 B
    const size_t SOFF = 134217728;
    uint8_t* S1 = ws + SOFF;                          // 37,879,808
    uint8_t* S2 = ws + SOFF;                          // 10,616,832 (alias; S1 dead)
    uint8_t* S3 = ws + SOFF + 10616832;               // 21,233,664
    uint8_t* S4 = ws + SOFF;                          //  6,553,600 (S2 dead)
    uint8_t* S5 = ws + SOFF + 6553600;                // 13,107,200 (S3 dead)
    uint8_t* S6 = ws + SOFF + 19660800;               //  4,718,592
    float*   stats = (float*)(ws + SOFF + 37879808);  // 8 KB
    float*   h     = (float*)(ws + SOFF + 37879808 + 8192);      // 524,288
    uint8_t* shb   = ws + SOFF + 37879808 + 8192 + 524288;       // 131,072
    uint16_t* Wp   = (uint16_t*)(shb + 131072);
    uint16_t* Wp2p = Wp;
    uint16_t* Wp3p = Wp + 29952;
    uint16_t* Wp4p = Wp + 89856;
    uint16_t* Wp5p = Wp + 209664;
    uint16_t* Wp6p = Wp + 449280;
    uint16_t* Wfc1 = Wp + 928512;

    prep_all_kernel<<<(549376 + 255) / 256, 256, 0, stream>>>(
        W2, W3, W4, W5, W6, FC1W, Wp2p, Wp3p, Wp4p, Wp5p, Wp6p, Wfc1, stats);
    border_all_kernel<<<(5177344 + 255) / 256, 256, 0, stream>>>(S1, S2, S3, S4, S5, S6);

    const int TN = T_STEPS * NBATCH;  // 1024

    // ---- layer 1: conv(3->32) over N only (T-invariant), BN, LIF ----
    {
        conv1_kernel<<<dim3(NBATCH, 4), 256, 0, stream>>>(x, W1, Bi1, Y,
                                                          stats + 0, stats + 128);
        bnlif1_pad_kernel<<<(NBATCH * 1024 * 8) / 256, 256, 0, stream>>>(
            Y, stats + 0, stats + 128, G1, BE1, S1, 1.0f / 131072.0f);
    }
    // ---- layer 2: conv(32->32) 32x32, ROWS=8 (27.5KB LDS, 5 blk/CU) ----
    {
        conv_mfma_kernel<32, 32, 32, 32, 8, 1, 2, 1><<<dim3(TN * 4, 1), 256, 0, stream>>>(
            S1, Wp2p, Bi2, Y, stats + 256, stats + 384);
        bnlifpool_pad_kernel<32, 32, 32><<<(NBATCH * 16 * 16 * 8) / 256, 256, 0, stream>>>(
            Y, stats + 256, stats + 384, G2, BE2, S2, 1.0f / (1024.0f * 1024.0f));
    }
    // ---- layer 3: conv(32->64) 16x16, 2 img/block, 32 co/block (R13 cfg) ----
    {
        conv_mfma_kernel<32, 64, 16, 16, 16, 2, 2, 1><<<dim3(TN / 2, 2), 256, 0, stream>>>(
            S2, Wp3p, Bi3, Y, stats + 512, stats + 640);
        bnlif_pad_kernel<64, 16, 16><<<(NBATCH * 256 * 16) / 256, 256, 0, stream>>>(
            Y, stats + 512, stats + 640, G3, BE3, S3, 1.0f / (1024.0f * 256.0f));
    }
    // ---- layer 4: conv(64->64) 16x16, 32 co/block, K-split 2 (R13 cfg) ----
    {
        conv_mfma_kernel<64, 64, 16, 16, 16, 1, 2, 2><<<dim3(TN, 2), 256, 0, stream>>>(
            S3, Wp4p, Bi4, Y, stats + 768, stats + 896);
        bnlifpool_pad_kernel<64, 16, 16><<<(NBATCH * 8 * 8 * 16) / 256, 256, 0, stream>>>(
            Y, stats + 768, stats + 896, G4, BE4, S4, 1.0f / (1024.0f * 256.0f));
    }
    // ---- layer 5: conv(64->128) 8x8, 2 img/block, 32 co/block, K-split 2 ----
    {
        conv_mfma_kernel<64, 128, 8, 8, 8, 2, 2, 2><<<dim3(TN / 2, 4), 256, 0, stream>>>(
            S4, Wp5p, Bi5, Y, stats + 1024, stats + 1152);
        bnlif_pad_kernel<128, 8, 8><<<(NBATCH * 64 * 32) / 256, 256, 0, stream>>>(
            Y, stats + 1024, stats + 1152, G5, BE5, S5, 1.0f / (1024.0f * 64.0f));
    }
    // ---- layer 6: conv(128->128) 8x8, 2 img/block, 32 co/block, K-split 4 ----
    {
        conv_mfma_kernel<128, 128, 8, 8, 8, 2, 2, 4><<<dim3(TN / 2, 4), 256, 0, stream>>>(
            S5, Wp6p, Bi6, Y, stats + 1280, stats + 1408);
        bnlifpool_pad_kernel<128, 8, 8><<<(NBATCH * 4 * 4 * 32) / 256, 256, 0, stream>>>(
            Y, stats + 1280, stats + 1408, G6, BE6, S6, 1.0f / (1024.0f * 64.0f));
    }
    // ---- fc1 (2048->128) via MFMA + LIF ----
    fc1_mfma_kernel<<<dim3(64, 2), 256, 0, stream>>>(S6, Wfc1, FC1B, h);
    lif_fc_kernel<<<(NBATCH * 128 + 255) / 256, 256, 0, stream>>>(h, shb, NBATCH * 128);
    // ---- fc2 (128->10) + LIF + mean ----
    fc2_kernel<<<(NBATCH * 10 + 255) / 256, 256, 0, stream>>>(shb, FC2W, FC2B, (float*)d_out);
}

// Round 16
// 612.864 us; speedup vs baseline: 1.0424x; 1.0132x over previous
//
#include <hip/hip_runtime.h>
#include <stdint.h>

// ---------------------------------------------------------------------------
// EnhancedSNNCifar: T=8 SNN forward.
// R16: layer-2 Y round-trip eliminated. R15's conv2 was byte-floor-bound:
//      132MB Y write + 134MB Y read-back (bnlifpool) for 2.6MB of spikes.
//      Now: pass A = same conv2 kernel with WRITE_Y=false (stats only);
//      pass B = conv2_fused_kernel: per (n, row-tile) block loops t=0..7,
//      recomputes y bit-identically in registers, applies BN+LIF (v-state in
//      registers across t) + 2x2 pool, writes only pooled u8 spikes.
//      Other layers unchanged from R15. Math identical -> absmax 0.0.
// ---------------------------------------------------------------------------

#define T_STEPS 8
#define NBATCH 128

typedef __attribute__((ext_vector_type(8))) short short8;
typedef __attribute__((ext_vector_type(4))) float f32x4;

__device__ __forceinline__ uint16_t f2bf(float f) {
    uint32_t x = __float_as_uint(f);
    uint32_t r = x + 0x7FFFu + ((x >> 16) & 1u);
    return (uint16_t)(r >> 16);
}
__device__ __forceinline__ float bf2f(uint16_t h) {
    return __uint_as_float(((uint32_t)h) << 16);
}

// ---------------------------------------------------------------------------
// Merged weight prep (5 convs + fc1) + stats zeroing, triple-bf16-split.
// ---------------------------------------------------------------------------
__device__ __forceinline__ void tsplit(float v, uint16_t& h1, uint16_t& h2, uint16_t& h3) {
    h1 = f2bf(v);
    const float r1 = v - bf2f(h1);
    h2 = f2bf(r1);
    const float r2 = r1 - bf2f(h2);
    h3 = f2bf(r2);
}

__device__ __forceinline__ void prep_conv_one(const float* __restrict__ w,
                                              uint16_t* __restrict__ wp, int i, int CIN) {
    const int KC = CIN >> 5;
    const int sh = i % 9;
    const int ci = (i / 9) % CIN;
    const int co = i / (9 * CIN);
    uint16_t h1, h2, h3;
    tsplit(w[i], h1, h2, h3);
    uint16_t* base = wp + (size_t)((co >> 4) * KC + (ci >> 5)) * 14976
                        + sh * 1664 + (co & 15) * 104 + (ci & 31);
    base[0] = h1;
    base[32] = h2;
    base[64] = h3;
}

__device__ __forceinline__ void prep_fc1_one(const float* __restrict__ w,
                                             uint16_t* __restrict__ wp, int i) {
    const int kp = i & 2047;
    const int o = i >> 11;
    const int px = kp >> 7, c = kp & 127;
    uint16_t h1, h2, h3;
    tsplit(w[o * 2048 + c * 16 + px], h1, h2, h3);
    uint16_t* base = wp + (size_t)((o >> 4) * 64 + (kp >> 5)) * 1664
                        + (o & 15) * 104 + (kp & 31);
    base[0] = h1;
    base[32] = h2;
    base[64] = h3;
}

__global__ void prep_all_kernel(const float* __restrict__ W2, const float* __restrict__ W3,
                                const float* __restrict__ W4, const float* __restrict__ W5,
                                const float* __restrict__ W6, const float* __restrict__ F1,
                                uint16_t* __restrict__ P2, uint16_t* __restrict__ P3,
                                uint16_t* __restrict__ P4, uint16_t* __restrict__ P5,
                                uint16_t* __restrict__ P6, uint16_t* __restrict__ PF,
                                float* __restrict__ stats) {
    int i = blockIdx.x * blockDim.x + threadIdx.x;
    if (i < 1536) { stats[i] = 0.0f; return; }
    i -= 1536;
    if (i < 9216) { prep_conv_one(W2, P2, i, 32); return; }
    i -= 9216;
    if (i < 18432) { prep_conv_one(W3, P3, i, 32); return; }
    i -= 18432;
    if (i < 36864) { prep_conv_one(W4, P4, i, 64); return; }
    i -= 36864;
    if (i < 73728) { prep_conv_one(W5, P5, i, 64); return; }
    i -= 73728;
    if (i < 147456) { prep_conv_one(W6, P6, i, 128); return; }
    i -= 147456;
    if (i < 262144) prep_fc1_one(F1, PF, i);
}

// Merged halo-border zeroing for all 6 u8 spike arrays (4 ch per thread).
__global__ void border_all_kernel(uint8_t* S1, uint8_t* S2, uint8_t* S3,
                                  uint8_t* S4, uint8_t* S5, uint8_t* S6) {
    int i = blockIdx.x * blockDim.x + threadIdx.x;
    uint8_t* s;
    int C, HP, WPP;
    if (i < 1081344) { s = S1; C = 32; HP = 34; WPP = 34; }
    else if ((i -= 1081344) < 557056) { s = S2; C = 32; HP = 18; WPP = 18; }
    else if ((i -= 557056) < 1114112) { s = S3; C = 64; HP = 18; WPP = 18; }
    else if ((i -= 1114112) < 589824) { s = S4; C = 64; HP = 10; WPP = 10; }
    else if ((i -= 589824) < 1179648) { s = S5; C = 128; HP = 10; WPP = 10; }
    else if ((i -= 1179648) < 655360) { s = S6; C = 128; HP = 6; WPP = 6; }
    else return;
    const int C4 = C >> 2;
    const int NB = 2 * WPP + 2 * (HP - 2);
    const int c4 = i % C4;
    const int b = (i / C4) % NB;
    const int img = i / (C4 * NB);
    int py, px;
    if (b < WPP) { py = 0; px = b; }
    else if (b < 2 * WPP) { py = HP - 1; px = b - WPP; }
    else { const int r = b - 2 * WPP; py = 1 + (r >> 1); px = (r & 1) ? (WPP - 1) : 0; }
    *(uint32_t*)&s[(size_t)img * (HP * WPP * C) + (py * WPP + px) * C + 4 * c4] = 0u;
}

// ---------------------------------------------------------------------------
// conv1 (3->32, 32x32, fp32 NCHW input): block 256 = 8 strips x 32 co.
// ---------------------------------------------------------------------------
__global__ __launch_bounds__(256) void conv1_kernel(
    const float* __restrict__ x, const float* __restrict__ w,
    const float* __restrict__ bias, float* __restrict__ y,
    float* __restrict__ ssum, float* __restrict__ ssq)
{
    __shared__ float tile[3][10][34];
    __shared__ float bnl[64];
    const int tid = threadIdx.x;
    const int m = blockIdx.x;
    const int y0 = blockIdx.y * 8;
    const int co = tid & 31;
    const int strip = tid >> 5;

    if (tid < 64) bnl[tid] = 0.0f;
    for (int i = tid; i < 3 * 10 * 34; i += 256) ((float*)tile)[i] = 0.0f;
    __syncthreads();

    {
        const int gy0 = (y0 == 0) ? 0 : y0 - 1;
        const int gy1 = (y0 + 8 > 31) ? 31 : y0 + 8;
        const int nrows = gy1 - gy0 + 1;
        for (int i = tid; i < 3 * nrows * 32; i += 256) {
            const int gx = i & 31;
            const int r = (i >> 5) % nrows;
            const int ci = i / (32 * nrows);
            const int gy = gy0 + r;
            tile[ci][gy - y0 + 1][gx + 1] =
                x[((size_t)m * 3 + ci) * 1024 + gy * 32 + gx];
        }
    }
    __syncthreads();

    float wr[27];
#pragma unroll
    for (int j = 0; j < 27; ++j) wr[j] = w[co * 27 + j];
    const float bv = bias[co];

    float lsum = 0.0f, lsq = 0.0f;
#pragma unroll
    for (int g = 0; g < 8; ++g) {
        float s[3][3][6];
#pragma unroll
        for (int ci = 0; ci < 3; ++ci)
#pragma unroll
            for (int ky = 0; ky < 3; ++ky)
#pragma unroll
                for (int c = 0; c < 6; ++c)
                    s[ci][ky][c] = tile[ci][g + ky][strip * 4 + c];
#pragma unroll
        for (int r = 0; r < 4; ++r) {
            float acc = bv;
#pragma unroll
            for (int ci = 0; ci < 3; ++ci)
#pragma unroll
                for (int ky = 0; ky < 3; ++ky)
#pragma unroll
                    for (int kx = 0; kx < 3; ++kx)
                        acc += s[ci][ky][r + kx] * wr[ci * 9 + ky * 3 + kx];
            const int lx = strip * 4 + r;
            y[(((size_t)m * 1024) + (y0 + g) * 32 + lx) * 32 + co] = acc;
            lsum += acc;
            lsq += acc * acc;
        }
    }
    atomicAdd(&bnl[co], lsum);
    atomicAdd(&bnl[32 + co], lsq);
    __syncthreads();
    if (tid < 32) atomicAdd(&ssum[tid], bnl[tid]);
    else if (tid < 64) atomicAdd(&ssq[tid - 32], bnl[tid]);
}

// ---------------------------------------------------------------------------
// MFMA spike conv. in: padded u8 spikes [m][(H+2)(W+2)][CIN] (halo zero).
// WRITE_Y=false -> stats-only pass (y never stored).
// ---------------------------------------------------------------------------
template <int CIN, int COUT, int H, int W, int ROWS, int IMPB, int NCO, int KSPLIT,
          bool WRITE_Y = true>
__global__ __launch_bounds__(256) void conv_mfma_kernel(
    const uint8_t* __restrict__ in, const uint16_t* __restrict__ wp,
    const float* __restrict__ bias, float* __restrict__ y,
    float* __restrict__ ssum, float* __restrict__ ssq)
{
    constexpr int KC = CIN / 32;
    constexpr int WPP = W + 2;
    constexpr int HW = H * W;
    constexpr int PXU16 = CIN + 8;
    constexpr int ISTR_B = (H + 2) * WPP * CIN;
    constexpr int RB = H / ROWS;
    constexpr int NSTRIP = IMPB * ROWS * W / 16;
    constexpr int MSPLIT = 4 / KSPLIT;
    constexpr int SPW = NSTRIP / MSPLIT;
    constexpr int TILE_U16 = IMPB * (ROWS + 2) * WPP * PXU16;
    constexpr int TILE_B = IMPB * (ROWS + 2) * WPP * CIN;
    constexpr int NIT = KC * 9;
    constexpr int ITW = NIT / KSPLIT;
    constexpr int CS = NCO * 16 + 1;
    static_assert(IMPB == 1 || ROWS == H, "impb needs full-image tiles");
    static_assert(NSTRIP % MSPLIT == 0 && NSTRIP % 4 == 0, "strips");
    static_assert(NIT % KSPLIT == 0, "ksplit");
    static_assert(TILE_B % 16 == 0, "tile u8 16B");
    static_assert(KSPLIT == 1 || TILE_U16 * 2 >= NSTRIP * 16 * CS * 4, "C fits");

    __shared__ __align__(16) uint16_t sp[TILE_U16];
    __shared__ float bn[NCO * 32];

    const int tid = threadIdx.x;
    const int lane = tid & 63;
    const int wav = tid >> 6;
    const int kg = wav / MSPLIT;
    const int mg = wav - kg * MSPLIT;
    const int col = lane & 15;
    const int quad = lane >> 4;

    const int m0 = (blockIdx.x / RB) * IMPB;
    const int ybase = (blockIdx.x % RB) * ROWS;

    if (tid < NCO * 32) bn[tid] = 0.0f;

    {
        const uint8_t* src = in + (size_t)m0 * ISTR_B + (size_t)ybase * WPP * CIN;
        for (int i = tid; i < TILE_B / 16; i += 256) {
            const uint4 v = ((const uint4*)src)[i];
            const int b = i * 16;
            const int px = b / CIN;
            const int ci = b - px * CIN;
            uint32_t* d = (uint32_t*)&sp[px * PXU16 + ci];
            d[0] = ((v.x & 1u) | (((v.x >> 8) & 1u) << 16)) * 0x3F80u;
            d[1] = (((v.x >> 16) & 1u) | (((v.x >> 24) & 1u) << 16)) * 0x3F80u;
            d[2] = ((v.y & 1u) | (((v.y >> 8) & 1u) << 16)) * 0x3F80u;
            d[3] = (((v.y >> 16) & 1u) | (((v.y >> 24) & 1u) << 16)) * 0x3F80u;
            d[4] = ((v.z & 1u) | (((v.z >> 8) & 1u) << 16)) * 0x3F80u;
            d[5] = (((v.z >> 16) & 1u) | (((v.z >> 24) & 1u) << 16)) * 0x3F80u;
            d[6] = ((v.w & 1u) | (((v.w >> 8) & 1u) << 16)) * 0x3F80u;
            d[7] = (((v.w >> 16) & 1u) | (((v.w >> 24) & 1u) << 16)) * 0x3F80u;
        }
    }
    __syncthreads();

    int abase[SPW];
#pragma unroll
    for (int s = 0; s < SPW; ++s) {
        const int p = (mg * SPW + s) * 16 + col;
        const int img = p / (ROWS * W);
        const int rem = p % (ROWS * W);
        abase[s] = ((img * (ROWS + 2) + rem / W) * WPP + rem % W) * PXU16 + quad * 8;
    }

    f32x4 acc[SPW][NCO];
#pragma unroll
    for (int s = 0; s < SPW; ++s)
#pragma unroll
        for (int j = 0; j < NCO; ++j) acc[s][j] = (f32x4)0.0f;

    const uint16_t* wbase = wp + ((size_t)blockIdx.y * NCO * KC) * 14976
                               + col * 104 + quad * 8;

    auto loadB = [&](short8 (&buf)[NCO][3], int it) {
        const int kc = it / 9, sh = it - kc * 9;
#pragma unroll
        for (int j = 0; j < NCO; ++j) {
            const uint16_t* p = wbase + (size_t)(j * KC + kc) * 14976 + sh * 1664;
            buf[j][0] = *(const short8*)p;
            buf[j][1] = *(const short8*)(p + 32);
            buf[j][2] = *(const short8*)(p + 64);
        }
    };
    auto mfmaStep = [&](short8 (&buf)[NCO][3], int it) {
        const int kc = it / 9, sh = it - kc * 9;
        const int dy = sh / 3, dx = sh - dy * 3;
        const int shoff = (dy * WPP + dx) * PXU16 + kc * 32;
#pragma unroll
        for (int s = 0; s < SPW; ++s) {
            const short8 a = *(const short8*)&sp[abase[s] + shoff];
#pragma unroll
            for (int j = 0; j < NCO; ++j) {
                f32x4 t = acc[s][j];
                t = __builtin_amdgcn_mfma_f32_16x16x32_bf16(a, buf[j][0], t, 0, 0, 0);
                t = __builtin_amdgcn_mfma_f32_16x16x32_bf16(a, buf[j][1], t, 0, 0, 0);
                t = __builtin_amdgcn_mfma_f32_16x16x32_bf16(a, buf[j][2], t, 0, 0, 0);
                acc[s][j] = t;
            }
        }
    };

    short8 bufA[NCO][3], bufB[NCO][3];
    const int it0 = kg * ITW, it1 = it0 + ITW;
    loadB(bufA, it0);
    int it = it0;
#pragma unroll 1
    for (; it + 2 <= it1; it += 2) {
        loadB(bufB, it + 1);
        mfmaStep(bufA, it);
        if (it + 2 < it1) loadB(bufA, it + 2);
        mfmaStep(bufB, it + 1);
    }
    if (it < it1) mfmaStep(bufA, it);

    float bv[NCO];
#pragma unroll
    for (int j = 0; j < NCO; ++j) bv[j] = bias[(blockIdx.y * NCO + j) * 16 + col];

    if constexpr (KSPLIT == 1) {
#pragma unroll
        for (int s = 0; s < SPW; ++s) {
            const int pb_ = (mg * SPW + s) * 16 + quad * 4;
            float sum[NCO], sq[NCO];
#pragma unroll
            for (int j = 0; j < NCO; ++j) { sum[j] = 0.0f; sq[j] = 0.0f; }
#pragma unroll
            for (int r = 0; r < 4; ++r) {
                const int p = pb_ + r;
                const int img = p / (ROWS * W);
                const int pxim = p % (ROWS * W) + ybase * W;
                float* yp = &y[((size_t)(m0 + img) * HW + pxim) * COUT
                               + blockIdx.y * NCO * 16 + col];
#pragma unroll
                for (int j = 0; j < NCO; ++j) {
                    const float v = acc[s][j][r] + bv[j];
                    if constexpr (WRITE_Y) yp[j * 16] = v;
                    sum[j] += v;
                    sq[j] += v * v;
                }
            }
#pragma unroll
            for (int j = 0; j < NCO; ++j) {
                float su = sum[j], s2 = sq[j];
                su += __shfl_xor(su, 16, 64);
                su += __shfl_xor(su, 32, 64);
                s2 += __shfl_xor(s2, 16, 64);
                s2 += __shfl_xor(s2, 32, 64);
                if (quad == 0) {
                    atomicAdd(&bn[j * 32 + col], su);
                    atomicAdd(&bn[j * 32 + 16 + col], s2);
                }
            }
        }
    } else {
        float* Csh = (float*)sp;
        __syncthreads();
        if (kg == 0) {
#pragma unroll
            for (int s = 0; s < SPW; ++s)
#pragma unroll
                for (int j = 0; j < NCO; ++j)
#pragma unroll
                    for (int r = 0; r < 4; ++r)
                        Csh[((mg * SPW + s) * 16 + quad * 4 + r) * CS + j * 16 + col]
                            = acc[s][j][r];
        }
        __syncthreads();
#pragma unroll
        for (int k = 1; k < KSPLIT; ++k) {
            if (kg == k) {
#pragma unroll
                for (int s = 0; s < SPW; ++s)
#pragma unroll
                    for (int j = 0; j < NCO; ++j)
#pragma unroll
                        for (int r = 0; r < 4; ++r)
                            Csh[((mg * SPW + s) * 16 + quad * 4 + r) * CS + j * 16 + col]
                                += acc[s][j][r];
            }
            __syncthreads();
        }
        constexpr int ES = NSTRIP / 4;
#pragma unroll
        for (int s2i = 0; s2i < ES; ++s2i) {
            const int gs = wav * ES + s2i;
            float sum[NCO], sq[NCO];
#pragma unroll
            for (int j = 0; j < NCO; ++j) { sum[j] = 0.0f; sq[j] = 0.0f; }
#pragma unroll
            for (int r = 0; r < 4; ++r) {
                const int p = gs * 16 + quad * 4 + r;
                const int img = p / (ROWS * W);
                const int pxim = p % (ROWS * W) + ybase * W;
                float* yp = &y[((size_t)(m0 + img) * HW + pxim) * COUT
                               + blockIdx.y * NCO * 16 + col];
#pragma unroll
                for (int j = 0; j < NCO; ++j) {
                    const float v = Csh[p * CS + j * 16 + col] + bv[j];
                    if constexpr (WRITE_Y) yp[j * 16] = v;
                    sum[j] += v;
                    sq[j] += v * v;
                }
            }
#pragma unroll
            for (int j = 0; j < NCO; ++j) {
                float su = sum[j], s2 = sq[j];
                su += __shfl_xor(su, 16, 64);
                su += __shfl_xor(su, 32, 64);
                s2 += __shfl_xor(s2, 16, 64);
                s2 += __shfl_xor(s2, 32, 64);
                if (quad == 0) {
                    atomicAdd(&bn[j * 32 + col], su);
                    atomicAdd(&bn[j * 32 + 16 + col], s2);
                }
            }
        }
    }
    __syncthreads();
    if (tid < NCO * 32) {
        const int j = tid >> 5, r = tid & 31;
        const int co0 = (blockIdx.y * NCO + j) * 16;
        if (r < 16) atomicAdd(&ssum[co0 + r], bn[j * 32 + r]);
        else atomicAdd(&ssq[co0 + r - 16], bn[j * 32 + r]);
    }
}

// ---------------------------------------------------------------------------
// conv2 fused pass B: per (n, row-tile) block loops t=0..7: stage A tile,
// recompute y in registers (identical MFMA sequence), BN+LIF (v across t),
// 2x2 pool, write pooled u8 spikes. No Y traffic.
// Block 256 = 4 waves; wave mg owns strips mg*4..mg*4+3 (rows mg*2,mg*2+1
// of the 8-row tile) -> pool pairs complete per thread.
// ---------------------------------------------------------------------------
__global__ __launch_bounds__(256) void conv2_fused_kernel(
    const uint8_t* __restrict__ in, const uint16_t* __restrict__ wp,
    const float* __restrict__ bias,
    const float* __restrict__ ssum, const float* __restrict__ ssq,
    const float* __restrict__ g, const float* __restrict__ be,
    uint8_t* __restrict__ sout, float invM)
{
    constexpr int WPP = 34, PXU16 = 40;
    constexpr int TILE_U16 = 10 * 34 * 40;
    constexpr int TILE_B = 10 * 34 * 32;
    constexpr int ISTR_B = 34 * 34 * 32;
    constexpr int OSTR = 18 * 18 * 32;
    __shared__ __align__(16) uint16_t sp[TILE_U16];

    const int tid = threadIdx.x;
    const int lane = tid & 63, wav = tid >> 6;
    const int col = lane & 15, quad = lane >> 4;
    const int n = blockIdx.x >> 2;
    const int rt = blockIdx.x & 3;
    const int ybase = rt * 8;

    // BN params for lane's channels c = j*16+col (same exprs as bnlifpool)
    float inv[2], shf[2], bv[2];
#pragma unroll
    for (int j = 0; j < 2; ++j) {
        const int c = j * 16 + col;
        const float m = ssum[c] * invM;
        inv[j] = g[c] / sqrtf(ssq[c] * invM - m * m + 1e-5f);
        shf[j] = be[c] - m * inv[j];
        bv[j] = bias[c];
    }

    int abase[4];
#pragma unroll
    for (int s = 0; s < 4; ++s) {
        const int p = (wav * 4 + s) * 16 + col;
        abase[s] = ((p >> 5) * WPP + (p & 31)) * PXU16 + quad * 8;
    }

    const uint16_t* wbase = wp + col * 104 + quad * 8;

    float vst[4][2][4];
#pragma unroll
    for (int s = 0; s < 4; ++s)
#pragma unroll
        for (int j = 0; j < 2; ++j)
#pragma unroll
            for (int r = 0; r < 4; ++r) vst[s][j][r] = 0.0f;

    const size_t ot = (size_t)NBATCH * OSTR;

#pragma unroll 1
    for (int t = 0; t < T_STEPS; ++t) {
        // stage A tile for m = t*128+n
        {
            const uint8_t* src = in + (size_t)(t * NBATCH + n) * ISTR_B
                                 + (size_t)ybase * WPP * 32;
            for (int i = tid; i < TILE_B / 16; i += 256) {
                const uint4 v = ((const uint4*)src)[i];
                const int b = i * 16;
                const int px = b >> 5;
                const int ci = b & 31;
                uint32_t* d = (uint32_t*)&sp[px * PXU16 + ci];
                d[0] = ((v.x & 1u) | (((v.x >> 8) & 1u) << 16)) * 0x3F80u;
                d[1] = (((v.x >> 16) & 1u) | (((v.x >> 24) & 1u) << 16)) * 0x3F80u;
                d[2] = ((v.y & 1u) | (((v.y >> 8) & 1u) << 16)) * 0x3F80u;
                d[3] = (((v.y >> 16) & 1u) | (((v.y >> 24) & 1u) << 16)) * 0x3F80u;
                d[4] = ((v.z & 1u) | (((v.z >> 8) & 1u) << 16)) * 0x3F80u;
                d[5] = (((v.z >> 16) & 1u) | (((v.z >> 24) & 1u) << 16)) * 0x3F80u;
                d[6] = ((v.w & 1u) | (((v.w >> 8) & 1u) << 16)) * 0x3F80u;
                d[7] = (((v.w >> 16) & 1u) | (((v.w >> 24) & 1u) << 16)) * 0x3F80u;
            }
        }
        __syncthreads();

        f32x4 acc[4][2];
#pragma unroll
        for (int s = 0; s < 4; ++s)
#pragma unroll
            for (int j = 0; j < 2; ++j) acc[s][j] = (f32x4)0.0f;

        auto loadB = [&](short8 (&buf)[2][3], int it) {
#pragma unroll
            for (int j = 0; j < 2; ++j) {
                const uint16_t* p = wbase + (size_t)j * 14976 + it * 1664;
                buf[j][0] = *(const short8*)p;
                buf[j][1] = *(const short8*)(p + 32);
                buf[j][2] = *(const short8*)(p + 64);
            }
        };
        auto mfmaStep = [&](short8 (&buf)[2][3], int it) {
            const int dy = it / 3, dx = it - dy * 3;
            const int shoff = (dy * WPP + dx) * PXU16;
#pragma unroll
            for (int s = 0; s < 4; ++s) {
                const short8 a = *(const short8*)&sp[abase[s] + shoff];
#pragma unroll
                for (int j = 0; j < 2; ++j) {
                    f32x4 tt = acc[s][j];
                    tt = __builtin_amdgcn_mfma_f32_16x16x32_bf16(a, buf[j][0], tt, 0, 0, 0);
                    tt = __builtin_amdgcn_mfma_f32_16x16x32_bf16(a, buf[j][1], tt, 0, 0, 0);
                    tt = __builtin_amdgcn_mfma_f32_16x16x32_bf16(a, buf[j][2], tt, 0, 0, 0);
                    acc[s][j] = tt;
                }
            }
        };

        short8 bufA[2][3], bufB[2][3];
        loadB(bufA, 0);
        int it = 0;
#pragma unroll 1
        for (; it + 2 <= 9; it += 2) {
            loadB(bufB, it + 1);
            mfmaStep(bufA, it);
            if (it + 2 < 9) loadB(bufA, it + 2);
            mfmaStep(bufB, it + 1);
        }
        mfmaStep(bufA, 8);   // tail (NIT=9 odd)

        // BN + LIF + pool (spikes for this t)
        uint32_t spk[4][2];   // per strip,j: bits r0..r3
#pragma unroll
        for (int s = 0; s < 4; ++s)
#pragma unroll
            for (int j = 0; j < 2; ++j) {
                uint32_t bits = 0;
#pragma unroll
                for (int r = 0; r < 4; ++r) {
                    const float yv = acc[s][j][r] + bv[j];
                    const float z = yv * inv[j] + shf[j];
                    vst[s][j][r] += (z - vst[s][j][r]) * 0.5f;
                    if (vst[s][j][r] >= 1.0f) { vst[s][j][r] = 0.0f; bits |= 1u << r; }
                }
                spk[s][j] = bits;
            }
        // pool: strips s and s+2 (rows mg*2, mg*2+1), x-pairs (r0,r1),(r2,r3)
        const int prow = rt * 4 + wav;           // pooled row 0..15
#pragma unroll
        for (int s = 0; s < 2; ++s) {            // xh = s
#pragma unroll
            for (int rp = 0; rp < 2; ++rp) {
                const int px = s * 8 + quad * 2 + rp;
                uint8_t* op = &sout[t * ot + (size_t)n * OSTR
                                    + ((prow + 1) * 18 + px + 1) * 32 + col];
#pragma unroll
                for (int j = 0; j < 2; ++j) {
                    const uint32_t m4 = (spk[s][j] | spk[s + 2][j]) >> (2 * rp);
                    op[j * 16] = (uint8_t)((m4 | (m4 >> 1)) & 1u);
                }
            }
        }
        __syncthreads();   // tile reads done before next t restages
    }
}

// Layer-1 BN+LIF: y NHWC [N][1024][32] (T-invariant) -> padded u8 spikes.
__global__ void bnlif1_pad_kernel(const float* __restrict__ y,
                                  const float* __restrict__ ssum,
                                  const float* __restrict__ ssq,
                                  const float* __restrict__ g,
                                  const float* __restrict__ be,
                                  uint8_t* __restrict__ s, float invM) {
    constexpr int OSTR = 34 * 34 * 32;
    const int i = blockIdx.x * blockDim.x + threadIdx.x;
    if (i >= NBATCH * 1024 * 8) return;
    const int c4 = i & 7;
    const int px = (i >> 3) & 1023;
    const int n = i >> 13;
    const int c0 = 4 * c4;
    float z[4], v[4];
    const float4 q = *(const float4*)&y[((size_t)n * 1024 + px) * 32 + c0];
    const float* qf = (const float*)&q;
#pragma unroll
    for (int c = 0; c < 4; ++c) {
        const float m = ssum[c0 + c] * invM;
        const float inv = g[c0 + c] / sqrtf(ssq[c0 + c] * invM - m * m + 1e-5f);
        z[c] = qf[c] * inv + (be[c0 + c] - m * inv);
        v[c] = 0.0f;
    }
    const int pyy = px >> 5, pxx = px & 31;
    const size_t obase = (size_t)n * OSTR + ((pyy + 1) * 34 + pxx + 1) * 32 + c0;
    const size_t ot = (size_t)NBATCH * OSTR;
#pragma unroll
    for (int t = 0; t < T_STEPS; ++t) {
        uint32_t pk = 0;
#pragma unroll
        for (int c = 0; c < 4; ++c) {
            v[c] += (z[c] - v[c]) * 0.5f;
            if (v[c] >= 1.0f) { v[c] = 0.0f; pk |= 1u << (8 * c); }
        }
        *(uint32_t*)&s[t * ot + obase] = pk;
    }
}

// BN+LIF (no pool): y NHWC [T*N][HW][C] -> padded u8 spikes (4 ch/thread).
template <int C, int H, int W>
__global__ void bnlif_pad_kernel(const float* __restrict__ y,
                                 const float* __restrict__ ssum,
                                 const float* __restrict__ ssq,
                                 const float* __restrict__ g,
                                 const float* __restrict__ be,
                                 uint8_t* __restrict__ s, float invM) {
    constexpr int C4 = C / 4;
    constexpr int HW = H * W;
    constexpr int OSTR = (H + 2) * (W + 2) * C;
    const int i = blockIdx.x * blockDim.x + threadIdx.x;
    if (i >= NBATCH * HW * C4) return;
    const int c4 = i % C4;
    const int px = (i / C4) % HW;
    const int n = i / (C4 * HW);
    const int c0 = 4 * c4;
    float inv[4], sh[4], v[4];
#pragma unroll
    for (int c = 0; c < 4; ++c) {
        const float m = ssum[c0 + c] * invM;
        inv[c] = g[c0 + c] / sqrtf(ssq[c0 + c] * invM - m * m + 1e-5f);
        sh[c] = be[c0 + c] - m * inv[c];
        v[c] = 0.0f;
    }
    const size_t ybase = ((size_t)n * HW + px) * C + c0;
    const size_t tstride = (size_t)NBATCH * HW * C;
    const int pyy = px / W, pxx = px % W;
    const size_t obase = (size_t)n * OSTR + ((pyy + 1) * (W + 2) + pxx + 1) * C + c0;
    const size_t ot = (size_t)NBATCH * OSTR;
#pragma unroll
    for (int t = 0; t < T_STEPS; ++t) {
        const float4 q = *(const float4*)&y[t * tstride + ybase];
        const float* qf = (const float*)&q;
        uint32_t pk = 0;
#pragma unroll
        for (int c = 0; c < 4; ++c) {
            const float z = qf[c] * inv[c] + sh[c];
            v[c] += (z - v[c]) * 0.5f;
            if (v[c] >= 1.0f) { v[c] = 0.0f; pk |= 1u << (8 * c); }
        }
        *(uint32_t*)&s[t * ot + obase] = pk;
    }
}

// BN+LIF + 2x2 max-pool (OR of spikes): y NHWC -> padded u8 (4 ch x 4 px/thread).
template <int C, int H, int W>
__global__ void bnlifpool_pad_kernel(const float* __restrict__ y,
                                     const float* __restrict__ ssum,
                                     const float* __restrict__ ssq,
                                     const float* __restrict__ g,
                                     const float* __restrict__ be,
                                     uint8_t* __restrict__ s, float invM) {
    constexpr int C4 = C / 4;
    constexpr int PH = H / 2, PW = W / 2;
    constexpr int OSTR = (PH + 2) * (PW + 2) * C;
    const int i = blockIdx.x * blockDim.x + threadIdx.x;
    if (i >= NBATCH * PH * PW * C4) return;
    const int c4 = i % C4;
    const int pw = (i / C4) % PW;
    const int ph = (i / (C4 * PW)) % PH;
    const int n = i / (C4 * PW * PH);
    const int c0 = 4 * c4;
    float inv[4], sh[4], v[4][4];
#pragma unroll
    for (int c = 0; c < 4; ++c) {
        const float m = ssum[c0 + c] * invM;
        inv[c] = g[c0 + c] / sqrtf(ssq[c0 + c] * invM - m * m + 1e-5f);
        sh[c] = be[c0 + c] - m * inv[c];
#pragma unroll
        for (int p = 0; p < 4; ++p) v[p][c] = 0.0f;
    }
    const size_t base = (((size_t)n * H + 2 * ph) * W + 2 * pw) * C + c0;
    const size_t tstride = (size_t)NBATCH * H * W * C;
    const size_t obase = (size_t)n * OSTR + ((ph + 1) * (PW + 2) + pw + 1) * C + c0;
    const size_t ot = (size_t)NBATCH * OSTR;
#pragma unroll
    for (int t = 0; t < T_STEPS; ++t) {
        const float* yt = y + t * tstride + base;
        float4 q[4];
        q[0] = *(const float4*)&yt[0];
        q[1] = *(const float4*)&yt[C];
        q[2] = *(const float4*)&yt[(size_t)W * C];
        q[3] = *(const float4*)&yt[(size_t)W * C + C];
        uint32_t pk = 0;
#pragma unroll
        for (int p = 0; p < 4; ++p) {
            const float* qf = (const float*)&q[p];
#pragma unroll
            for (int c = 0; c < 4; ++c) {
                const float z = qf[c] * inv[c] + sh[c];
                v[p][c] += (z - v[p][c]) * 0.5f;
                if (v[p][c] >= 1.0f) { v[p][c] = 0.0f; pk |= 1u << (8 * c); }
            }
        }
        *(uint32_t*)&s[t * ot + obase] = pk;
    }
}

// fc1 as MFMA GEMM.
__global__ __launch_bounds__(256) void fc1_mfma_kernel(
    const uint8_t* __restrict__ f, const uint16_t* __restrict__ wfc,
    const float* __restrict__ b, float* __restrict__ h)
{
    __shared__ __align__(16) uint16_t A[16 * 2056];
    const int tid = threadIdx.x;
    const int lane = tid & 63, wav = tid >> 6;
    const int col = lane & 15, quad = lane >> 4;
    const int r0 = blockIdx.x * 16;

    {
        const int row = tid >> 4, px = tid & 15;
        const int py = px >> 2, pxx = px & 3;
        const uint8_t* src = f + (size_t)(r0 + row) * 4608
                             + ((py + 1) * 6 + pxx + 1) * 128;
        uint32_t* dst = (uint32_t*)&A[row * 2056 + px * 128];
#pragma unroll
        for (int i = 0; i < 8; ++i) {
            const uint4 v = ((const uint4*)src)[i];
            dst[8 * i + 0] = ((v.x & 1u) | (((v.x >> 8) & 1u) << 16)) * 0x3F80u;
            dst[8 * i + 1] = (((v.x >> 16) & 1u) | (((v.x >> 24) & 1u) << 16)) * 0x3F80u;
            dst[8 * i + 2] = ((v.y & 1u) | (((v.y >> 8) & 1u) << 16)) * 0x3F80u;
            dst[8 * i + 3] = (((v.y >> 16) & 1u) | (((v.y >> 24) & 1u) << 16)) * 0x3F80u;
            dst[8 * i + 4] = ((v.z & 1u) | (((v.z >> 8) & 1u) << 16)) * 0x3F80u;
            dst[8 * i + 5] = (((v.z >> 16) & 1u) | (((v.z >> 24) & 1u) << 16)) * 0x3F80u;
            dst[8 * i + 6] = ((v.w & 1u) | (((v.w >> 8) & 1u) << 16)) * 0x3F80u;
            dst[8 * i + 7] = (((v.w >> 16) & 1u) | (((v.w >> 24) & 1u) << 16)) * 0x3F80u;
        }
    }
    __syncthreads();

    const int coblk = blockIdx.y * 4 + wav;
    const uint16_t* wbase = wfc + (size_t)coblk * 64 * 1664 + col * 104 + quad * 8;
    f32x4 acc = (f32x4)0.0f;

    auto loadB = [&](short8 (&buf)[3], int kc) {
        const uint16_t* p = wbase + kc * 1664;
        buf[0] = *(const short8*)p;
        buf[1] = *(const short8*)(p + 32);
        buf[2] = *(const short8*)(p + 64);
    };
    auto step = [&](short8 (&buf)[3], int kc) {
        const short8 a = *(const short8*)&A[col * 2056 + kc * 32 + quad * 8];
        acc = __builtin_amdgcn_mfma_f32_16x16x32_bf16(a, buf[0], acc, 0, 0, 0);
        acc = __builtin_amdgcn_mfma_f32_16x16x32_bf16(a, buf[1], acc, 0, 0, 0);
        acc = __builtin_amdgcn_mfma_f32_16x16x32_bf16(a, buf[2], acc, 0, 0, 0);
    };

    short8 bA[3], bB[3];
    loadB(bA, 0);
#pragma unroll 1
    for (int kc = 0; kc + 2 <= 64; kc += 2) {
        loadB(bB, kc + 1);
        step(bA, kc);
        if (kc + 2 < 64) loadB(bA, kc + 2);
        step(bB, kc + 1);
    }

    const int o = coblk * 16 + col;
    const float bv = b[o];
#pragma unroll
    for (int r = 0; r < 4; ++r)
        h[(size_t)(r0 + quad * 4 + r) * 128 + o] = acc[r] + bv;
}

// LIF over T for fc1 outputs.
__global__ void lif_fc_kernel(const float* __restrict__ h,
                              uint8_t* __restrict__ s, int NF) {
    const int i = blockIdx.x * blockDim.x + threadIdx.x;
    if (i >= NF) return;
    float v = 0.0f;
#pragma unroll
    for (int t = 0; t < T_STEPS; ++t) {
        const float z = h[(size_t)t * NF + i];
        v += (z - v) * 0.5f;
        const float sp = (v >= 1.0f) ? 1.0f : 0.0f;
        s[(size_t)t * NF + i] = (uint8_t)sp;
        v *= (1.0f - sp);
    }
}

// fc2 + LIF + mean over T.
__global__ void fc2_kernel(const uint8_t* __restrict__ sh,
                           const float* __restrict__ w,
                           const float* __restrict__ b,
                           float* __restrict__ out) {
    const int i = blockIdx.x * blockDim.x + threadIdx.x;
    if (i >= NBATCH * 10) return;
    const int k = i % 10;
    const int n = i / 10;
    float v = 0.0f, acc = 0.0f;
    for (int t = 0; t < T_STEPS; ++t) {
        const uint8_t* row = sh + ((size_t)t * NBATCH + n) * 128;
        float z = b[k];
        for (int o = 0; o < 128; ++o)
            z += (float)row[o] * w[k * 128 + o];
        v += (z - v) * 0.5f;
        const float sp = (v >= 1.0f) ? 1.0f : 0.0f;
        acc += sp;
        v *= (1.0f - sp);
    }
    out[i] = acc * (1.0f / T_STEPS);
}

extern "C" void kernel_launch(void* const* d_in, const int* in_sizes, int n_in,
                              void* d_out, int out_size, void* d_ws, size_t ws_size,
                              hipStream_t stream) {
    const float* x   = (const float*)d_in[0];
    const float* W1  = (const float*)d_in[1];
    const float* Bi1 = (const float*)d_in[2];
    const float* G1  = (const float*)d_in[3];
    const float* BE1 = (const float*)d_in[4];
    const float* W2  = (const float*)d_in[5];
    const float* Bi2 = (const float*)d_in[6];
    const float* G2  = (const float*)d_in[7];
    const float* BE2 = (const float*)d_in[8];
    const float* W3  = (const float*)d_in[9];
    const float* Bi3 = (const float*)d_in[10];
    const float* G3  = (const float*)d_in[11];
    const float* BE3 = (const float*)d_in[12];
    const float* W4  = (const float*)d_in[13];
    const float* Bi4 = (const float*)d_in[14];
    const float* G4  = (const float*)d_in[15];
    const float* BE4 = (const float*)d_in[16];
    const float* W5  = (const float*)d_in[17];
    const float* Bi5 = (const float*)d_in[18];
    const float* G5  = (const float*)d_in[19];
    const float* BE5 = (const float*)d_in[20];
    const float* W6  = (const float*)d_in[21];
    const float* Bi6 = (const float*)d_in[22];
    const float* G6  = (const float*)d_in[23];
    const float* BE6 = (const float*)d_in[24];
    const float* FC1W = (const float*)d_in[25];
    const float* FC1B = (const float*)d_in[26];
    const float* FC2W = (const float*)d_in[27];
    const float* FC2B = (const float*)d_in[28];

    // ---- workspace layout (≈176 MiB) ----
    uint8_t* ws = (uint8_t*)d_ws;
    float*   Y  = (float*)ws;                         // 134,217,728 B
    const size_t SOFF = 134217728;
    uint8_t* S1 = ws + SOFF;                          // 37,879,808
    uint8_t* S2 = ws + SOFF;                          // 10,616,832 (alias; S1 read in same kernels only)
    uint8_t* S3 = ws + SOFF + 10616832;               // 21,233,664
    uint8_t* S4 = ws + SOFF;                          //  6,553,600
    uint8_t* S5 = ws + SOFF + 6553600;                // 13,107,200
    uint8_t* S6 = ws + SOFF + 19660800;               //  4,718,592
    float*   stats = (float*)(ws + SOFF + 37879808);  // 8 KB
    float*   h     = (float*)(ws + SOFF + 37879808 + 8192);      // 524,288
    uint8_t* shb   = ws + SOFF + 37879808 + 8192 + 524288;       // 131,072
    uint16_t* Wp   = (uint16_t*)(shb + 131072);
    uint16_t* Wp2p = Wp;
    uint16_t* Wp3p = Wp + 29952;
    uint16_t* Wp4p = Wp + 89856;
    uint16_t* Wp5p = Wp + 209664;
    uint16_t* Wp6p = Wp + 449280;
    uint16_t* Wfc1 = Wp + 928512;

    prep_all_kernel<<<(549376 + 255) / 256, 256, 0, stream>>>(
        W2, W3, W4, W5, W6, FC1W, Wp2p, Wp3p, Wp4p, Wp5p, Wp6p, Wfc1, stats);
    border_all_kernel<<<(5177344 + 255) / 256, 256, 0, stream>>>(S1, S2, S3, S4, S5, S6);

    const int TN = T_STEPS * NBATCH;  // 1024

    // ---- layer 1: conv(3->32) over N only (T-invariant), BN, LIF ----
    {
        conv1_kernel<<<dim3(NBATCH, 4), 256, 0, stream>>>(x, W1, Bi1, Y,
                                                          stats + 0, stats + 128);
        bnlif1_pad_kernel<<<(NBATCH * 1024 * 8) / 256, 256, 0, stream>>>(
            Y, stats + 0, stats + 128, G1, BE1, S1, 1.0f / 131072.0f);
    }
    // ---- layer 2: conv(32->32) stats pass + fused recompute (no Y) ----
    {
        conv_mfma_kernel<32, 32, 32, 32, 8, 1, 2, 1, false>
            <<<dim3(TN * 4, 1), 256, 0, stream>>>(
                S1, Wp2p, Bi2, Y, stats + 256, stats + 384);
        conv2_fused_kernel<<<NBATCH * 4, 256, 0, stream>>>(
            S1, Wp2p, Bi2, stats + 256, stats + 384, G2, BE2, S2,
            1.0f / (1024.0f * 1024.0f));
    }
    // ---- layer 3: conv(32->64) 16x16, 2 img/block, 32 co/block ----
    {
        conv_mfma_kernel<32, 64, 16, 16, 16, 2, 2, 1><<<dim3(TN / 2, 2), 256, 0, stream>>>(
            S2, Wp3p, Bi3, Y, stats + 512, stats + 640);
        bnlif_pad_kernel<64, 16, 16><<<(NBATCH * 256 * 16) / 256, 256, 0, stream>>>(
            Y, stats + 512, stats + 640, G3, BE3, S3, 1.0f / (1024.0f * 256.0f));
    }
    // ---- layer 4: conv(64->64) 16x16, 32 co/block, K-split 2 ----
    {
        conv_mfma_kernel<64, 64, 16, 16, 16, 1, 2, 2><<<dim3(TN, 2), 256, 0, stream>>>(
            S3, Wp4p, Bi4, Y, stats + 768, stats + 896);
        bnlifpool_pad_kernel<64, 16, 16><<<(NBATCH * 8 * 8 * 16) / 256, 256, 0, stream>>>(
            Y, stats + 768, stats + 896, G4, BE4, S4, 1.0f / (1024.0f * 256.0f));
    }
    // ---- layer 5: conv(64->128) 8x8, 2 img/block, 32 co/block, K-split 2 ----
    {
        conv_mfma_kernel<64, 128, 8, 8, 8, 2, 2, 2><<<dim3(TN / 2, 4), 256, 0, stream>>>(
            S4, Wp5p, Bi5, Y, stats + 1024, stats + 1152);
        bnlif_pad_kernel<128, 8, 8><<<(NBATCH * 64 * 32) / 256, 256, 0, stream>>>(
            Y, stats + 1024, stats + 1152, G5, BE5, S5, 1.0f / (1024.0f * 64.0f));
    }
    // ---- layer 6: conv(128->128) 8x8, 2 img/block, 32 co/block, K-split 4 ----
    {
        conv_mfma_kernel<128, 128, 8, 8, 8, 2, 2, 4><<<dim3(TN / 2, 4), 256, 0, stream>>>(
            S5, Wp6p, Bi6, Y, stats + 1280, stats + 1408);
        bnlifpool_pad_kernel<128, 8, 8><<<(NBATCH * 4 * 4 * 32) / 256, 256, 0, stream>>>(
            Y, stats + 1280, stats + 1408, G6, BE6, S6, 1.0f / (1024.0f * 64.0f));
    }
    // ---- fc1 (2048->128) via MFMA + LIF ----
    fc1_mfma_kernel<<<dim3(64, 2), 256, 0, stream>>>(S6, Wfc1, FC1B, h);
    lif_fc_kernel<<<(NBATCH * 128 + 255) / 256, 256, 0, stream>>>(h, shb, NBATCH * 128);
    // ---- fc2 (128->10) + LIF + mean ----
    fc2_kernel<<<(NBATCH * 10 + 255) / 256, 256, 0, stream>>>(shb, FC2W, FC2B, (float*)d_out);
}